// Round 11
// baseline (4486.572 us; speedup 1.0000x reference)
//
#include <hip/hip_runtime.h>
#include <hip/hip_fp16.h>
#include <math.h>

// Workspace layout (float offsets)
#define WS_XIN   0L
#define WS_GF    65536L
#define WS_STATS 65536L      // [8][256][4][4] softmax partials
#define WS_BARS  98304L      // barrier region: 8192 unsigned words
#define WS_FS    589824L
#define WS_XO    720896L
#define WS_GX    851968L
#define WS_Q     1376256L    // fp16 [512][65536]
#define WS_WKH   18153472L   // fp16 [65536][256]
#define WS_WVE   34930688L
#define WS_BVE   34996224L
#define WS_KT    34996480L   // fp16 Kt[b][g][d]  (131072 float slots used)
#define WS_HH    35520768L   // [65][2048]
#define WS_C     35653888L
#define WS_OG    35655936L
#define WS_VW    35657984L

#define NBLK 256

typedef unsigned long long u64;

__device__ __forceinline__ float sigmf(float x){ return 1.0f/(1.0f + expf(-x)); }
__device__ __forceinline__ float dot4(float4 a, float4 b){
  return a.x*b.x + a.y*b.y + a.z*b.z + a.w*b.w;
}
__device__ __forceinline__ void h8_to_f8(uint4 v, float4& a, float4& b){
  const __half2* hp = (const __half2*)&v;
  float2 f0 = __half22float2(hp[0]);
  float2 f1 = __half22float2(hp[1]);
  float2 f2 = __half22float2(hp[2]);
  float2 f3 = __half22float2(hp[3]);
  a = make_float4(f0.x, f0.y, f1.x, f1.y);
  b = make_float4(f2.x, f2.y, f3.x, f3.y);
}
__device__ __forceinline__ float4 h4_to_f4(uint2 v){
  const __half2* hp = (const __half2*)&v;
  float2 f0 = __half22float2(hp[0]);
  float2 f1 = __half22float2(hp[1]);
  return make_float4(f0.x, f0.y, f1.x, f1.y);
}

// coherent (device-point) accesses for cross-block mutable data — AGENT scope
__device__ __forceinline__ float cld(const float* p){
  return __hip_atomic_load((float*)p, __ATOMIC_RELAXED, __HIP_MEMORY_SCOPE_AGENT);
}
__device__ __forceinline__ void cst(float* p, float v){
  __hip_atomic_store(p, v, __ATOMIC_RELAXED, __HIP_MEMORY_SCOPE_AGENT);
}
__device__ __forceinline__ float2 cld2(const float* p){
  u64 v = __hip_atomic_load((const u64*)p, __ATOMIC_RELAXED, __HIP_MEMORY_SCOPE_AGENT);
  float2 r;
  r.x = __uint_as_float((unsigned)(v & 0xffffffffu));
  r.y = __uint_as_float((unsigned)(v >> 32));
  return r;
}
__device__ __forceinline__ void cst2(float* p, float a, float b){
  u64 v = ((u64)__float_as_uint(b) << 32) | (u64)__float_as_uint(a);
  __hip_atomic_store((u64*)p, v, __ATOMIC_RELAXED, __HIP_MEMORY_SCOPE_AGENT);
}
__device__ __forceinline__ void csth2(unsigned* p, unsigned v){
  __hip_atomic_store(p, v, __ATOMIC_RELAXED, __HIP_MEMORY_SCOPE_AGENT);
}
__device__ __forceinline__ float4 cldh4(const __half* p){
  u64 v = __hip_atomic_load((const u64*)p, __ATOMIC_RELAXED, __HIP_MEMORY_SCOPE_AGENT);
  uint2 uv;
  uv.x = (unsigned)(v & 0xffffffffu);
  uv.y = (unsigned)(v >> 32);
  return h4_to_f4(uv);
}

// hierarchical grid barrier: 32 groups x 8 blocks, monotonic phase counters.
// bar layout (unsigned words): grpCnt[g] @ g*64; topCnt @ 2048; topGen @ 2112;
// grpGen[g] @ 2176 + g*64.
__device__ __forceinline__ void gbar(unsigned* bar, unsigned ph){
  __syncthreads();
  if (threadIdx.x == 0){
    const unsigned g = blockIdx.x & 31u;
    asm volatile("s_waitcnt vmcnt(0)" ::: "memory");
    unsigned old = __hip_atomic_fetch_add(&bar[g*64], 1u, __ATOMIC_RELAXED, __HIP_MEMORY_SCOPE_AGENT);
    if (old == ph*8u - 1u){
      unsigned t = __hip_atomic_fetch_add(&bar[2048], 1u, __ATOMIC_RELAXED, __HIP_MEMORY_SCOPE_AGENT);
      if (t == ph*32u - 1u)
        __hip_atomic_store(&bar[2112], ph, __ATOMIC_RELAXED, __HIP_MEMORY_SCOPE_AGENT);
    }
    if (blockIdx.x < 32){
      while (__hip_atomic_load(&bar[2112], __ATOMIC_RELAXED, __HIP_MEMORY_SCOPE_AGENT) < ph)
        __builtin_amdgcn_s_sleep(2);
      __hip_atomic_store(&bar[2176 + blockIdx.x*64], ph, __ATOMIC_RELAXED, __HIP_MEMORY_SCOPE_AGENT);
    } else {
      while (__hip_atomic_load(&bar[2176 + g*64], __ATOMIC_RELAXED, __HIP_MEMORY_SCOPE_AGENT) < ph)
        __builtin_amdgcn_s_sleep(2);
    }
  }
  __syncthreads();
}

// ---------------- init
__launch_bounds__(256)
__global__ void k_init(const float* __restrict__ x, float* __restrict__ ws){
  int i = blockIdx.x*256 + threadIdx.x;
  int r = i >> 7, m = i & 127;
  int t = r >> 3, b = r & 7;
  ws[WS_XIN + i] = x[b*8192 + m*64 + t];
  if (i < 2048){ ws[WS_HH + i] = 0.f; ws[WS_C + i] = 0.f; }
}

// ---------------- Wk -> fp16
__launch_bounds__(256)
__global__ void k_wk16(const float* __restrict__ in, __half* __restrict__ out){
  size_t i = ((size_t)blockIdx.x*256 + threadIdx.x)*8;
  float4 a = *(const float4*)(in + i);
  float4 b = *(const float4*)(in + i + 4);
  uint4 v;
  __half2* vp = (__half2*)&v;
  vp[0] = __floats2half2_rn(a.x, a.y);
  vp[1] = __floats2half2_rn(a.z, a.w);
  vp[2] = __floats2half2_rn(b.x, b.y);
  vp[3] = __floats2half2_rn(b.z, b.w);
  *(uint4*)(out + i) = v;
}

// ---------------- generic GEMM (act: 0 none, 1 relu, 2 sigmoid, 3 none+fp16 out)
__launch_bounds__(256)
__global__ void k_gemm_nt(const float* __restrict__ W, const float* __restrict__ X,
                          const float* __restrict__ b1, const float* __restrict__ b2,
                          float* __restrict__ out, int M, int K, int act){
  __shared__ float Wt[32*132];
  __shared__ float Xt[32*132];
  const int tid = threadIdx.x;
  const int tx = tid & 15, ty = tid >> 4;
  const int m0 = blockIdx.x * 128, n0 = blockIdx.y * 128;
  float acc[8][8];
  #pragma unroll
  for (int i = 0; i < 8; i++)
    #pragma unroll
    for (int j = 0; j < 8; j++) acc[i][j] = 0.f;

  for (int k0 = 0; k0 < K; k0 += 32){
    #pragma unroll
    for (int i = 0; i < 4; i++){
      int f4 = i*256 + tid;
      int row = f4 >> 3;
      int j4 = (f4 & 7) * 4;
      float4 w = *(const float4*)&W[(size_t)(m0+row)*K + k0 + j4];
      Wt[(j4+0)*132 + row] = w.x;
      Wt[(j4+1)*132 + row] = w.y;
      Wt[(j4+2)*132 + row] = w.z;
      Wt[(j4+3)*132 + row] = w.w;
      float4 xv = *(const float4*)&X[(size_t)(n0+row)*K + k0 + j4];
      Xt[(j4+0)*132 + row] = xv.x;
      Xt[(j4+1)*132 + row] = xv.y;
      Xt[(j4+2)*132 + row] = xv.z;
      Xt[(j4+3)*132 + row] = xv.w;
    }
    __syncthreads();
    for (int k = 0; k < 32; k++){
      float4 a0 = *(const float4*)&Wt[k*132 + 4*tx];
      float4 a1 = *(const float4*)&Wt[k*132 + 64 + 4*tx];
      float4 x0 = *(const float4*)&Xt[k*132 + 4*ty];
      float4 x1 = *(const float4*)&Xt[k*132 + 64 + 4*ty];
      float am[8] = {a0.x,a0.y,a0.z,a0.w,a1.x,a1.y,a1.z,a1.w};
      float xn[8] = {x0.x,x0.y,x0.z,x0.w,x1.x,x1.y,x1.z,x1.w};
      #pragma unroll
      for (int mi = 0; mi < 8; mi++)
        #pragma unroll
        for (int ni = 0; ni < 8; ni++)
          acc[mi][ni] += am[mi]*xn[ni];
    }
    __syncthreads();
  }

  float bvv[8];
  #pragma unroll
  for (int mi = 0; mi < 8; mi++){
    int m = m0 + ((mi < 4) ? (4*tx + mi) : (64 + 4*tx + mi - 4));
    float bb = b1[m];
    if (b2) bb += b2[m];
    bvv[mi] = bb;
  }
  #pragma unroll
  for (int ni = 0; ni < 8; ni++){
    int n = n0 + ((ni < 4) ? (4*ty + ni) : (64 + 4*ty + ni - 4));
    float v[8];
    #pragma unroll
    for (int mi = 0; mi < 8; mi++){
      float q = acc[mi][ni] + bvv[mi];
      if (act == 1) q = fmaxf(q, 0.f);
      else if (act == 2) q = 1.0f/(1.0f + expf(-q));
      v[mi] = q;
    }
    if (act == 3){
      __half* outh = (__half*)out;
      uint2 u0, u1;
      __half2* up0 = (__half2*)&u0;
      __half2* up1 = (__half2*)&u1;
      up0[0] = __floats2half2_rn(v[0], v[1]);
      up0[1] = __floats2half2_rn(v[2], v[3]);
      up1[0] = __floats2half2_rn(v[4], v[5]);
      up1[1] = __floats2half2_rn(v[6], v[7]);
      *(uint2*)&outh[(size_t)n*M + m0 + 4*tx]      = u0;
      *(uint2*)&outh[(size_t)n*M + m0 + 64 + 4*tx] = u1;
    } else {
      *(float4*)&out[(size_t)n*M + m0 + 4*tx]      = make_float4(v[0],v[1],v[2],v[3]);
      *(float4*)&out[(size_t)n*M + m0 + 64 + 4*tx] = make_float4(v[4],v[5],v[6],v[7]);
    }
  }
}

// ---------------- feature extractor conv chain
__launch_bounds__(256)
__global__ void k_feconv(const float* __restrict__ gf, const float* __restrict__ c1w,
                         const float* __restrict__ c1b, const float* __restrict__ c2w,
                         const float* __restrict__ c2b, const float* __restrict__ c3w,
                         const float* __restrict__ c3b, float* __restrict__ fs){
  __shared__ float fc[1024];
  __shared__ float p1[16*512];
  __shared__ float p2[32*256];
  __shared__ float w1[48], w2[1536], w3[96], bb1[16], bb2[32];
  const int r = blockIdx.x, tid = threadIdx.x;
  #pragma unroll
  for (int i = 0; i < 4; i++) fc[i*256 + tid] = gf[(size_t)r*1024 + i*256 + tid];
  if (tid < 48) w1[tid] = c1w[tid];
  if (tid < 16) bb1[tid] = c1b[tid];
  for (int i = tid; i < 1536; i += 256) w2[i] = c2w[i];
  if (tid < 32) bb2[tid] = c2b[tid];
  if (tid < 96) w3[tid] = c3w[tid];
  __syncthreads();
  for (int i = 0; i < 32; i++){
    int idx = i*256 + tid;
    int ch = idx >> 9, p = idx & 511;
    float k0 = w1[ch*3], k1 = w1[ch*3+1], k2 = w1[ch*3+2], bias = bb1[ch];
    int q = 2*p;
    float xm1 = (q >= 1) ? fc[q-1] : 0.f;
    float x0 = fc[q];
    float x1 = fc[q+1];
    float x2 = (q+2 < 1024) ? fc[q+2] : 0.f;
    float a0 = bias + k0*xm1 + k1*x0 + k2*x1;
    float a1 = bias + k0*x0 + k1*x1 + k2*x2;
    p1[ch*512 + p] = fmaxf(fmaxf(a0, 0.f), fmaxf(a1, 0.f));
  }
  __syncthreads();
  for (int i = 0; i < 32; i++){
    int idx = i*256 + tid;
    int ch = idx >> 8, p = idx & 255;
    float a0 = bb2[ch], a1 = bb2[ch];
    int q = 2*p;
    #pragma unroll
    for (int ci = 0; ci < 16; ci++){
      const float* wp = &w2[(ch*16+ci)*3];
      const float* ip = &p1[ci*512];
      float xm1 = (q >= 1) ? ip[q-1] : 0.f;
      float x0 = ip[q];
      float x1 = ip[q+1];
      float x2 = (q+2 < 512) ? ip[q+2] : 0.f;
      a0 += wp[0]*xm1 + wp[1]*x0 + wp[2]*x1;
      a1 += wp[0]*x0  + wp[1]*x1 + wp[2]*x2;
    }
    p2[ch*256 + p] = fmaxf(fmaxf(a0, 0.f), fmaxf(a1, 0.f));
  }
  __syncthreads();
  if (tid < 256){
    float a = c3b[0];
    const int l = tid;
    #pragma unroll
    for (int ci = 0; ci < 32; ci++){
      const float* wp = &w3[ci*3];
      const float* ip = &p2[ci*256];
      float xm1 = (l >= 1) ? ip[l-1] : 0.f;
      float x0 = ip[l];
      float x2 = (l+1 < 256) ? ip[l+1] : 0.f;
      a += wp[0]*xm1 + wp[1]*x0 + wp[2]*x2;
    }
    fs[(size_t)r*256 + l] = a;
  }
}

// ---------------- Wv_eff + barrier region init
__launch_bounds__(256)
__global__ void k_wveff(const float* __restrict__ Wv, const float* __restrict__ bvq,
                        const float* __restrict__ Wao, float* __restrict__ wve,
                        float* __restrict__ bve, unsigned* __restrict__ bar){
  __shared__ float wa[256];
  const int g = blockIdx.x, tid = threadIdx.x;
  if (g == 0){
    for (int i = tid; i < 8192; i += 256) bar[i] = 0u;
  }
  wa[tid] = Wao[tid];
  __syncthreads();
  float acc = 0.f;
  for (int d = 0; d < 256; d++)
    acc += Wv[((size_t)(g*256 + d))*256 + tid] * wa[d];
  wve[g*256 + tid] = acc;
  if (tid == 0){
    float s = 0.f;
    for (int d = 0; d < 256; d++) s += bvq[g*256 + d]*wa[d];
    bve[g] = s;
  }
}

// ---------------- persistent recurrent loop
__global__ __launch_bounds__(512, 2)
void k_loop(const float* __restrict__ gx, const float* __restrict__ Wh,
            const __half* __restrict__ wkh, const float* __restrict__ bkb,
            const float* __restrict__ wve, const float* __restrict__ bve,
            const __half* __restrict__ Qh, const float* __restrict__ bao,
            const float* __restrict__ Wout, const float* __restrict__ bout,
            float* __restrict__ c, float* __restrict__ og, float* __restrict__ vw,
            __half* __restrict__ Kth, float* __restrict__ stats, float* __restrict__ hH,
            float* __restrict__ y, unsigned* __restrict__ bar){
  __shared__ float S[25088];
  const int blk = blockIdx.x, tid = threadIdx.x;
  unsigned ph = 0;
  const float bao0 = bao[0];

  const int p1_b = blk >> 5, p1_s = blk & 31;
  const int gid  = blk;
  const int p3_b = blk >> 5, p3_ht = (blk >> 2) & 7, p3_gt = blk & 3;
  const int p3_h0 = p3_ht*32, p3_g0 = p3_gt*64;

  // hoist Wh fragment for P1
  float4 whr[4];
  int p1_row;
  {
    const int j = tid >> 4, part = tid & 15;
    const int rr = p1_s*32 + j, o = rr >> 2, gate = rr & 3;
    p1_row = gate*256 + o;
    const float4* wr = (const float4*)(Wh + (size_t)p1_row*256);
    #pragma unroll
    for (int u = 0; u < 4; u++) whr[u] = wr[u*16 + part];
  }

  // P2 thread mapping: jq = j-quarter, dp*2 = first of two adjacent d rows
  const int p2_jq = tid & 3, p2_dp = tid >> 2;
  const int p2_d0 = p2_dp*2;

  for (int t = 0; t < 64; t++){
    // ---------- P1 ----------
    if (t > 0){
      if (tid < 256){
        const float* sp = stats + ((size_t)p1_b*256 + tid)*16;
        float2 a0 = cld2(sp+0);  float2 b0 = cld2(sp+2);
        float2 a1 = cld2(sp+4);  float2 b1 = cld2(sp+6);
        float2 a2 = cld2(sp+8);  float2 b2 = cld2(sp+10);
        float2 a3 = cld2(sp+12); float2 b3 = cld2(sp+14);
        float m = fmaxf(fmaxf(a0.x, a1.x), fmaxf(a2.x, a3.x));
        float e0 = expf(a0.x - m), e1 = expf(a1.x - m), e2 = expf(a2.x - m), e3 = expf(a3.x - m);
        float den = a0.y*e0 + a1.y*e1 + a2.y*e2 + a3.y*e3;
        float num = b0.x*e0 + b1.x*e1 + b2.x*e2 + b3.x*e3;
        float hv = num/den + bao0;
        S[tid] = hv;
        if (p1_s == 0) cst(&hH[(size_t)t*2048 + p1_b*256 + tid], hv);
      }
    } else {
      if (tid < 256) S[tid] = 0.f;
    }
    __syncthreads();
    {
      const int j = tid >> 4, part = tid & 15;
      const float4* h4 = (const float4*)S;
      float a0 = 0.f;
      #pragma unroll
      for (int u = 0; u < 4; u++)
        a0 += dot4(whr[u], h4[u*16 + part]);
      a0 += __shfl_xor(a0, 1);
      a0 += __shfl_xor(a0, 2);
      a0 += __shfl_xor(a0, 4);
      a0 += __shfl_xor(a0, 8);
      if (part == 0) S[256 + j] = a0 + gx[(size_t)(t*8 + p1_b)*1024 + p1_row];
    }
    __syncthreads();
    if (tid < 8){
      const int o_ = p1_s*8 + tid, ci = p1_b*256 + o_;
      float ig = sigmf(S[256 + tid*4 + 0]);
      float fg = sigmf(S[256 + tid*4 + 1]);
      float gg = tanhf(S[256 + tid*4 + 2]);
      float ov = sigmf(S[256 + tid*4 + 3]);
      float cv = cld(&c[ci]);
      cst(&c[ci], fg*cv + ig*gg);
      cst(&og[ci], ov);
    }
    gbar(bar, ++ph);

    // ---------- P2: K[:, g=gid, :] = Wk16 . c (fp16 out) ; vw[:, gid] ----------
    {
      int bb0 = tid >> 6, j40 = tid & 63;
      float* dst = &S[bb0*260 + j40*4];
      const float* src = &c[bb0*256 + j40*4];
      float2 v0 = cld2(src);
      float2 v1 = cld2(src+2);
      dst[0] = v0.x; dst[1] = v0.y; dst[2] = v1.x; dst[3] = v1.y;
    }
    __syncthreads();
    if (tid < 64){
      const int bb = tid >> 3, part = tid & 7;
      const float4* wv4 = (const float4*)(wve + gid*256);
      float sacc = 0.f;
      #pragma unroll
      for (int u = 0; u < 8; u++){
        float4 w = wv4[part*8 + u];
        const float* op = &og[bb*256 + (part*8 + u)*4];
        float2 o0 = cld2(op);
        float2 o1 = cld2(op+2);
        sacc += w.x*o0.x + w.y*o0.y + w.z*o1.x + w.w*o1.y;
      }
      sacc += __shfl_xor(sacc, 1);
      sacc += __shfl_xor(sacc, 2);
      sacc += __shfl_xor(sacc, 4);
      if (part == 0) cst(&vw[bb*256 + gid], sacc + bve[gid]);
    }
    {
      const float4* cl4 = (const float4*)S;
      const __half* wr0 = wkh + ((size_t)gid*256 + p2_d0)*256 + p2_jq*64;
      const __half* wr1 = wr0 + 256;
      float acc0[8], acc1[8];
      #pragma unroll
      for (int b = 0; b < 8; b++){ acc0[b] = 0.f; acc1[b] = 0.f; }
      #pragma unroll 4
      for (int u = 0; u < 16; u++){
        const int uu = (u + p2_jq) & 15;         // bank-conflict-free rotation
        float4 w0 = h4_to_f4(*(const uint2*)(wr0 + uu*4));
        float4 w1 = h4_to_f4(*(const uint2*)(wr1 + uu*4));
        const float4* cb = cl4 + p2_jq*16 + uu;
        #pragma unroll
        for (int b = 0; b < 8; b++){
          float4 c4 = cb[b*65];
          acc0[b] += dot4(w0, c4);
          acc1[b] += dot4(w1, c4);
        }
      }
      #pragma unroll
      for (int b = 0; b < 8; b++){
        acc0[b] += __shfl_xor(acc0[b], 1);
        acc0[b] += __shfl_xor(acc0[b], 2);
        acc1[b] += __shfl_xor(acc1[b], 1);
        acc1[b] += __shfl_xor(acc1[b], 2);
      }
      if (p2_jq == 0){
        const float bk0 = bkb[gid*256 + p2_d0];
        const float bk1 = bkb[gid*256 + p2_d0 + 1];
        #pragma unroll
        for (int b = 0; b < 8; b++){
          __half2 hv = __floats2half2_rn(acc0[b] + bk0, acc1[b] + bk1);
          csth2((unsigned*)&Kth[(size_t)b*65536 + gid*256 + p2_d0], *(unsigned*)&hv);
        }
      }
    }
    gbar(bar, ++ph);

    // ---------- P3: partial attention stats for (b, 32h, 64g) ----------
    {
      const __half* Qb = Qh + ((size_t)(t*8 + p3_b))*65536 + (size_t)p3_h0*256;
      #pragma unroll
      for (int i = 0; i < 2; i++){
        int f8 = i*512 + tid;
        int hh = f8 >> 5, j8 = f8 & 31;
        uint4 v = *(const uint4*)(Qb + hh*256 + j8*8);
        float4 a, b;
        h8_to_f8(v, a, b);
        float* dst = &S[hh*260 + j8*8];
        *(float4*)dst = a;
        *(float4*)(dst+4) = b;
      }
      const __half* Kbh = Kth + (size_t)p3_b*65536 + (size_t)p3_g0*256;
      float* Kl = S + 8320;
      #pragma unroll
      for (int i = 0; i < 8; i++){
        int f = i*512 + tid;                 // [0,4096) u64 chunks
        int gg = f >> 6, c4i = f & 63;
        float4 v = cldh4(Kbh + gg*256 + c4i*4);
        *(float4*)&Kl[gg*260 + c4i*4] = v;
      }
      if (tid < 64) S[24960 + tid] = cld(&vw[p3_b*256 + p3_g0 + tid]);
      __syncthreads();
      const int kh = tid >> 7, r = tid & 127, ty = r >> 4, txl = r & 15;
      float acc[4][4];
      #pragma unroll
      for (int a = 0; a < 4; a++)
        #pragma unroll
        for (int i = 0; i < 4; i++) acc[a][i] = 0.f;
      const float4* Ql4 = (const float4*)S;
      const float4* Kl4 = (const float4*)(S + 8320);
      for (int k4 = 0; k4 < 16; k4++){
        const int kk = kh*16 + k4;
        float4 qv[4], kv[4];
        #pragma unroll
        for (int a = 0; a < 4; a++) qv[a] = Ql4[(ty + 8*a)*65 + kk];
        #pragma unroll
        for (int i = 0; i < 4; i++) kv[i] = Kl4[(txl + 16*i)*65 + kk];
        #pragma unroll
        for (int a = 0; a < 4; a++)
          #pragma unroll
          for (int i = 0; i < 4; i++)
            acc[a][i] += dot4(qv[a], kv[i]);
      }
      __syncthreads();
      float* Pl = S;
      if (kh > 0){
        #pragma unroll
        for (int a = 0; a < 4; a++)
          #pragma unroll
          for (int i = 0; i < 4; i++)
            Pl[(kh-1)*2048 + r*16 + a*4 + i] = acc[a][i];
      }
      __syncthreads();
      if (kh == 0){
        #pragma unroll
        for (int p = 0; p < 3; p++)
          #pragma unroll
          for (int a = 0; a < 4; a++)
            #pragma unroll
            for (int i = 0; i < 4; i++)
              acc[a][i] += Pl[p*2048 + r*16 + a*4 + i];
        #pragma unroll
        for (int a = 0; a < 4; a++)
          #pragma unroll
          for (int i = 0; i < 4; i++)
            acc[a][i] *= 0.0625f;
        #pragma unroll
        for (int a = 0; a < 4; a++){
          float mx = fmaxf(fmaxf(acc[a][0], acc[a][1]), fmaxf(acc[a][2], acc[a][3]));
          mx = fmaxf(mx, __shfl_xor(mx, 1));
          mx = fmaxf(mx, __shfl_xor(mx, 2));
          mx = fmaxf(mx, __shfl_xor(mx, 4));
          mx = fmaxf(mx, __shfl_xor(mx, 8));
          float den = 0.f, num = 0.f;
          #pragma unroll
          for (int i = 0; i < 4; i++){
            float pv = expf(acc[a][i] - mx);
            den += pv;
            num += pv * S[24960 + txl + 16*i];
          }
          den += __shfl_xor(den, 1); num += __shfl_xor(num, 1);
          den += __shfl_xor(den, 2); num += __shfl_xor(num, 2);
          den += __shfl_xor(den, 4); num += __shfl_xor(num, 4);
          den += __shfl_xor(den, 8); num += __shfl_xor(num, 8);
          if (txl == 0){
            const int h = p3_h0 + ty + 8*a;
            float* sp = &stats[(((size_t)p3_b*256 + h)*4 + p3_gt)*4];
            cst2(sp, mx, den);
            cst(sp+2, num);
          }
        }
      }
    }
    gbar(bar, ++ph);
  }

  // ---------- tail ----------
  if (p1_s == 0 && tid < 256){
    const float* sp = stats + ((size_t)p1_b*256 + tid)*16;
    float2 a0 = cld2(sp+0);  float2 b0 = cld2(sp+2);
    float2 a1 = cld2(sp+4);  float2 b1 = cld2(sp+6);
    float2 a2 = cld2(sp+8);  float2 b2 = cld2(sp+10);
    float2 a3 = cld2(sp+12); float2 b3 = cld2(sp+14);
    float m = fmaxf(fmaxf(a0.x, a1.x), fmaxf(a2.x, a3.x));
    float e0 = expf(a0.x - m), e1 = expf(a1.x - m), e2 = expf(a2.x - m), e3 = expf(a3.x - m);
    float den = a0.y*e0 + a1.y*e1 + a2.y*e2 + a3.y*e3;
    float num = b0.x*e0 + b1.x*e1 + b2.x*e2 + b3.x*e3;
    cst(&hH[(size_t)64*2048 + p1_b*256 + tid], num/den + bao0);
  }
  gbar(bar, ++ph);
  if (blk < 64 && tid < 80){
    const int t2 = blk;
    const int bb2 = tid/10, cc = tid - bb2*10;
    const float* hr = &hH[(size_t)(t2+1)*2048 + bb2*256];
    const float* wr2 = &Wout[cc*256];
    float acc = 0.f;
    for (int u = 0; u < 128; u++){
      float2 h2 = cld2(hr + u*2);
      acc += h2.x*wr2[u*2] + h2.y*wr2[u*2+1];
    }
    y[bb2*640 + cc*64 + t2] = acc + bout[cc];
  }
}

extern "C" void kernel_launch(void* const* d_in, const int* in_sizes, int n_in,
                              void* d_out, int out_size, void* d_ws, size_t ws_size,
                              hipStream_t stream){
  (void)in_sizes; (void)n_in; (void)out_size; (void)ws_size;
  const float* x      = (const float*)d_in[0];
  const float* w_init = (const float*)d_in[1];
  const float* b_init = (const float*)d_in[2];
  const float* c1w    = (const float*)d_in[3];
  const float* c1b    = (const float*)d_in[4];
  const float* c2w    = (const float*)d_in[5];
  const float* c2b    = (const float*)d_in[6];
  const float* c3w    = (const float*)d_in[7];
  const float* c3b    = (const float*)d_in[8];
  const float* Wx     = (const float*)d_in[9];
  const float* bx     = (const float*)d_in[10];
  const float* Wh     = (const float*)d_in[11];
  const float* bh     = (const float*)d_in[12];
  const float* Wxo    = (const float*)d_in[13];
  const float* bxo    = (const float*)d_in[14];
  const float* Wq     = (const float*)d_in[15];
  const float* bq     = (const float*)d_in[16];
  const float* Wk     = (const float*)d_in[17];
  const float* bk_    = (const float*)d_in[18];
  const float* Wv     = (const float*)d_in[19];
  const float* bv     = (const float*)d_in[20];
  const float* Wao    = (const float*)d_in[21];
  const float* bao    = (const float*)d_in[22];
  const float* Wout   = (const float*)d_in[23];
  const float* bout   = (const float*)d_in[24];
  float* y  = (float*)d_out;
  float* ws = (float*)d_ws;

  float* xin   = ws + WS_XIN;
  float* gf    = ws + WS_GF;
  float* stats = ws + WS_STATS;
  unsigned* bar = (unsigned*)(ws + WS_BARS);
  float* fs    = ws + WS_FS;
  float* xo    = ws + WS_XO;
  float* gxp   = ws + WS_GX;
  __half* Qh   = (__half*)(ws + WS_Q);
  __half* wkh  = (__half*)(ws + WS_WKH);
  float* wve   = ws + WS_WVE;
  float* bve   = ws + WS_BVE;
  __half* Kth  = (__half*)(ws + WS_KT);
  float* hH    = ws + WS_HH;
  float* cp    = ws + WS_C;
  float* ogp   = ws + WS_OG;
  float* vwp   = ws + WS_VW;

  k_init<<<256, 256, 0, stream>>>(x, ws);
  k_wk16<<<8192, 256, 0, stream>>>(Wk, wkh);
  k_gemm_nt<<<dim3(8, 4), 256, 0, stream>>>(w_init, xin, b_init, nullptr, gf, 1024, 128, 1);
  k_feconv<<<512, 256, 0, stream>>>(gf, c1w, c1b, c2w, c2b, c3w, c3b, fs);
  k_gemm_nt<<<dim3(2, 4), 256, 0, stream>>>(Wxo, fs, bxo, nullptr, xo, 256, 256, 2);
  k_gemm_nt<<<dim3(8, 4), 256, 0, stream>>>(Wx, fs, bx, bh, gxp, 1024, 256, 0);
  k_wveff<<<256, 256, 0, stream>>>(Wv, bv, Wao, wve, bve, bar);
  k_gemm_nt<<<dim3(512, 4), 256, 0, stream>>>(Wq, xo, bq, nullptr, (float*)Qh, 65536, 256, 3);
  k_loop<<<NBLK, 512, 0, stream>>>(gxp, Wh, wkh, bk_, wve, bve, Qh, bao, Wout, bout,
                                   cp, ogp, vwp, Kth, stats, hH, y, bar);
}

// Round 12
// 2840.893 us; speedup vs baseline: 1.5793x; 1.5793x over previous
//
#include <hip/hip_runtime.h>
#include <hip/hip_fp16.h>
#include <math.h>

// Workspace layout (float offsets)
#define WS_XIN   0L
#define WS_GF    65536L
#define WS_STATS 65536L      // [8][256][4][4] softmax partials
#define WS_BARS  98304L      // barrier region: 8192 unsigned words
#define WS_FS    589824L
#define WS_XO    720896L
#define WS_GX    851968L
#define WS_Q     1376256L    // fp16 [512][65536]
#define WS_WKH   18153472L   // fp16 [65536][256]
#define WS_WVE   34930688L
#define WS_BVE   34996224L
#define WS_KT    34996480L   // fp16 Kt[b][g][d]
#define WS_HH    35520768L   // [65][2048]
#define WS_C     35653888L
#define WS_OG    35655936L
#define WS_VW    35657984L

#define NBLK 256

typedef unsigned long long u64;

__device__ __forceinline__ float sigmf(float x){ return 1.0f/(1.0f + expf(-x)); }
__device__ __forceinline__ float dot4(float4 a, float4 b){
  return a.x*b.x + a.y*b.y + a.z*b.z + a.w*b.w;
}
__device__ __forceinline__ void h8_to_f8(uint4 v, float4& a, float4& b){
  const __half2* hp = (const __half2*)&v;
  float2 f0 = __half22float2(hp[0]);
  float2 f1 = __half22float2(hp[1]);
  float2 f2 = __half22float2(hp[2]);
  float2 f3 = __half22float2(hp[3]);
  a = make_float4(f0.x, f0.y, f1.x, f1.y);
  b = make_float4(f2.x, f2.y, f3.x, f3.y);
}
__device__ __forceinline__ float4 h4_to_f4(uint2 v){
  const __half2* hp = (const __half2*)&v;
  float2 f0 = __half22float2(hp[0]);
  float2 f1 = __half22float2(hp[1]);
  return make_float4(f0.x, f0.y, f1.x, f1.y);
}

// coherent (device-point) accesses for cross-block mutable data — AGENT scope
__device__ __forceinline__ float cld(const float* p){
  return __hip_atomic_load((float*)p, __ATOMIC_RELAXED, __HIP_MEMORY_SCOPE_AGENT);
}
__device__ __forceinline__ void cst(float* p, float v){
  __hip_atomic_store(p, v, __ATOMIC_RELAXED, __HIP_MEMORY_SCOPE_AGENT);
}
__device__ __forceinline__ float2 cld2(const float* p){
  u64 v = __hip_atomic_load((const u64*)p, __ATOMIC_RELAXED, __HIP_MEMORY_SCOPE_AGENT);
  float2 r;
  r.x = __uint_as_float((unsigned)(v & 0xffffffffu));
  r.y = __uint_as_float((unsigned)(v >> 32));
  return r;
}
__device__ __forceinline__ void cst2(float* p, float a, float b){
  u64 v = ((u64)__float_as_uint(b) << 32) | (u64)__float_as_uint(a);
  __hip_atomic_store((u64*)p, v, __ATOMIC_RELAXED, __HIP_MEMORY_SCOPE_AGENT);
}
__device__ __forceinline__ void csth2(unsigned* p, unsigned v){
  __hip_atomic_store(p, v, __ATOMIC_RELAXED, __HIP_MEMORY_SCOPE_AGENT);
}
__device__ __forceinline__ float4 cldh4(const __half* p){
  u64 v = __hip_atomic_load((const u64*)p, __ATOMIC_RELAXED, __HIP_MEMORY_SCOPE_AGENT);
  uint2 uv;
  uv.x = (unsigned)(v & 0xffffffffu);
  uv.y = (unsigned)(v >> 32);
  return h4_to_f4(uv);
}

// hierarchical grid barrier: 32 groups x 8 blocks, monotonic phase counters.
__device__ __forceinline__ void gbar(unsigned* bar, unsigned ph){
  __syncthreads();
  if (threadIdx.x == 0){
    const unsigned g = blockIdx.x & 31u;
    asm volatile("s_waitcnt vmcnt(0)" ::: "memory");
    unsigned old = __hip_atomic_fetch_add(&bar[g*64], 1u, __ATOMIC_RELAXED, __HIP_MEMORY_SCOPE_AGENT);
    if (old == ph*8u - 1u){
      unsigned t = __hip_atomic_fetch_add(&bar[2048], 1u, __ATOMIC_RELAXED, __HIP_MEMORY_SCOPE_AGENT);
      if (t == ph*32u - 1u)
        __hip_atomic_store(&bar[2112], ph, __ATOMIC_RELAXED, __HIP_MEMORY_SCOPE_AGENT);
    }
    if (blockIdx.x < 32){
      while (__hip_atomic_load(&bar[2112], __ATOMIC_RELAXED, __HIP_MEMORY_SCOPE_AGENT) < ph)
        __builtin_amdgcn_s_sleep(2);
      __hip_atomic_store(&bar[2176 + blockIdx.x*64], ph, __ATOMIC_RELAXED, __HIP_MEMORY_SCOPE_AGENT);
    } else {
      while (__hip_atomic_load(&bar[2176 + g*64], __ATOMIC_RELAXED, __HIP_MEMORY_SCOPE_AGENT) < ph)
        __builtin_amdgcn_s_sleep(2);
    }
  }
  __syncthreads();
}

// ---------------- init
__launch_bounds__(256)
__global__ void k_init(const float* __restrict__ x, float* __restrict__ ws){
  int i = blockIdx.x*256 + threadIdx.x;
  int r = i >> 7, m = i & 127;
  int t = r >> 3, b = r & 7;
  ws[WS_XIN + i] = x[b*8192 + m*64 + t];
  if (i < 2048){ ws[WS_HH + i] = 0.f; ws[WS_C + i] = 0.f; }
}

// ---------------- Wk -> fp16
__launch_bounds__(256)
__global__ void k_wk16(const float* __restrict__ in, __half* __restrict__ out){
  size_t i = ((size_t)blockIdx.x*256 + threadIdx.x)*8;
  float4 a = *(const float4*)(in + i);
  float4 b = *(const float4*)(in + i + 4);
  uint4 v;
  __half2* vp = (__half2*)&v;
  vp[0] = __floats2half2_rn(a.x, a.y);
  vp[1] = __floats2half2_rn(a.z, a.w);
  vp[2] = __floats2half2_rn(b.x, b.y);
  vp[3] = __floats2half2_rn(b.z, b.w);
  *(uint4*)(out + i) = v;
}

// ---------------- generic GEMM (act: 0 none, 1 relu, 2 sigmoid, 3 none+fp16 out)
__launch_bounds__(256)
__global__ void k_gemm_nt(const float* __restrict__ W, const float* __restrict__ X,
                          const float* __restrict__ b1, const float* __restrict__ b2,
                          float* __restrict__ out, int M, int K, int act){
  __shared__ float Wt[32*132];
  __shared__ float Xt[32*132];
  const int tid = threadIdx.x;
  const int tx = tid & 15, ty = tid >> 4;
  const int m0 = blockIdx.x * 128, n0 = blockIdx.y * 128;
  float acc[8][8];
  #pragma unroll
  for (int i = 0; i < 8; i++)
    #pragma unroll
    for (int j = 0; j < 8; j++) acc[i][j] = 0.f;

  for (int k0 = 0; k0 < K; k0 += 32){
    #pragma unroll
    for (int i = 0; i < 4; i++){
      int f4 = i*256 + tid;
      int row = f4 >> 3;
      int j4 = (f4 & 7) * 4;
      float4 w = *(const float4*)&W[(size_t)(m0+row)*K + k0 + j4];
      Wt[(j4+0)*132 + row] = w.x;
      Wt[(j4+1)*132 + row] = w.y;
      Wt[(j4+2)*132 + row] = w.z;
      Wt[(j4+3)*132 + row] = w.w;
      float4 xv = *(const float4*)&X[(size_t)(n0+row)*K + k0 + j4];
      Xt[(j4+0)*132 + row] = xv.x;
      Xt[(j4+1)*132 + row] = xv.y;
      Xt[(j4+2)*132 + row] = xv.z;
      Xt[(j4+3)*132 + row] = xv.w;
    }
    __syncthreads();
    for (int k = 0; k < 32; k++){
      float4 a0 = *(const float4*)&Wt[k*132 + 4*tx];
      float4 a1 = *(const float4*)&Wt[k*132 + 64 + 4*tx];
      float4 x0 = *(const float4*)&Xt[k*132 + 4*ty];
      float4 x1 = *(const float4*)&Xt[k*132 + 64 + 4*ty];
      float am[8] = {a0.x,a0.y,a0.z,a0.w,a1.x,a1.y,a1.z,a1.w};
      float xn[8] = {x0.x,x0.y,x0.z,x0.w,x1.x,x1.y,x1.z,x1.w};
      #pragma unroll
      for (int mi = 0; mi < 8; mi++)
        #pragma unroll
        for (int ni = 0; ni < 8; ni++)
          acc[mi][ni] += am[mi]*xn[ni];
    }
    __syncthreads();
  }

  float bvv[8];
  #pragma unroll
  for (int mi = 0; mi < 8; mi++){
    int m = m0 + ((mi < 4) ? (4*tx + mi) : (64 + 4*tx + mi - 4));
    float bb = b1[m];
    if (b2) bb += b2[m];
    bvv[mi] = bb;
  }
  #pragma unroll
  for (int ni = 0; ni < 8; ni++){
    int n = n0 + ((ni < 4) ? (4*ty + ni) : (64 + 4*ty + ni - 4));
    float v[8];
    #pragma unroll
    for (int mi = 0; mi < 8; mi++){
      float q = acc[mi][ni] + bvv[mi];
      if (act == 1) q = fmaxf(q, 0.f);
      else if (act == 2) q = 1.0f/(1.0f + expf(-q));
      v[mi] = q;
    }
    if (act == 3){
      __half* outh = (__half*)out;
      uint2 u0, u1;
      __half2* up0 = (__half2*)&u0;
      __half2* up1 = (__half2*)&u1;
      up0[0] = __floats2half2_rn(v[0], v[1]);
      up0[1] = __floats2half2_rn(v[2], v[3]);
      up1[0] = __floats2half2_rn(v[4], v[5]);
      up1[1] = __floats2half2_rn(v[6], v[7]);
      *(uint2*)&outh[(size_t)n*M + m0 + 4*tx]      = u0;
      *(uint2*)&outh[(size_t)n*M + m0 + 64 + 4*tx] = u1;
    } else {
      *(float4*)&out[(size_t)n*M + m0 + 4*tx]      = make_float4(v[0],v[1],v[2],v[3]);
      *(float4*)&out[(size_t)n*M + m0 + 64 + 4*tx] = make_float4(v[4],v[5],v[6],v[7]);
    }
  }
}

// ---------------- feature extractor conv chain
__launch_bounds__(256)
__global__ void k_feconv(const float* __restrict__ gf, const float* __restrict__ c1w,
                         const float* __restrict__ c1b, const float* __restrict__ c2w,
                         const float* __restrict__ c2b, const float* __restrict__ c3w,
                         const float* __restrict__ c3b, float* __restrict__ fs){
  __shared__ float fc[1024];
  __shared__ float p1[16*512];
  __shared__ float p2[32*256];
  __shared__ float w1[48], w2[1536], w3[96], bb1[16], bb2[32];
  const int r = blockIdx.x, tid = threadIdx.x;
  #pragma unroll
  for (int i = 0; i < 4; i++) fc[i*256 + tid] = gf[(size_t)r*1024 + i*256 + tid];
  if (tid < 48) w1[tid] = c1w[tid];
  if (tid < 16) bb1[tid] = c1b[tid];
  for (int i = tid; i < 1536; i += 256) w2[i] = c2w[i];
  if (tid < 32) bb2[tid] = c2b[tid];
  if (tid < 96) w3[tid] = c3w[tid];
  __syncthreads();
  for (int i = 0; i < 32; i++){
    int idx = i*256 + tid;
    int ch = idx >> 9, p = idx & 511;
    float k0 = w1[ch*3], k1 = w1[ch*3+1], k2 = w1[ch*3+2], bias = bb1[ch];
    int q = 2*p;
    float xm1 = (q >= 1) ? fc[q-1] : 0.f;
    float x0 = fc[q];
    float x1 = fc[q+1];
    float x2 = (q+2 < 1024) ? fc[q+2] : 0.f;
    float a0 = bias + k0*xm1 + k1*x0 + k2*x1;
    float a1 = bias + k0*x0 + k1*x1 + k2*x2;
    p1[ch*512 + p] = fmaxf(fmaxf(a0, 0.f), fmaxf(a1, 0.f));
  }
  __syncthreads();
  for (int i = 0; i < 32; i++){
    int idx = i*256 + tid;
    int ch = idx >> 8, p = idx & 255;
    float a0 = bb2[ch], a1 = bb2[ch];
    int q = 2*p;
    #pragma unroll
    for (int ci = 0; ci < 16; ci++){
      const float* wp = &w2[(ch*16+ci)*3];
      const float* ip = &p1[ci*512];
      float xm1 = (q >= 1) ? ip[q-1] : 0.f;
      float x0 = ip[q];
      float x1 = ip[q+1];
      float x2 = (q+2 < 512) ? ip[q+2] : 0.f;
      a0 += wp[0]*xm1 + wp[1]*x0 + wp[2]*x1;
      a1 += wp[0]*x0  + wp[1]*x1 + wp[2]*x2;
    }
    p2[ch*256 + p] = fmaxf(fmaxf(a0, 0.f), fmaxf(a1, 0.f));
  }
  __syncthreads();
  if (tid < 256){
    float a = c3b[0];
    const int l = tid;
    #pragma unroll
    for (int ci = 0; ci < 32; ci++){
      const float* wp = &w3[ci*3];
      const float* ip = &p2[ci*256];
      float xm1 = (l >= 1) ? ip[l-1] : 0.f;
      float x0 = ip[l];
      float x2 = (l+1 < 256) ? ip[l+1] : 0.f;
      a += wp[0]*xm1 + wp[1]*x0 + wp[2]*x2;
    }
    fs[(size_t)r*256 + l] = a;
  }
}

// ---------------- Wv_eff + barrier region init
__launch_bounds__(256)
__global__ void k_wveff(const float* __restrict__ Wv, const float* __restrict__ bvq,
                        const float* __restrict__ Wao, float* __restrict__ wve,
                        float* __restrict__ bve, unsigned* __restrict__ bar){
  __shared__ float wa[256];
  const int g = blockIdx.x, tid = threadIdx.x;
  if (g == 0){
    for (int i = tid; i < 8192; i += 256) bar[i] = 0u;
  }
  wa[tid] = Wao[tid];
  __syncthreads();
  float acc = 0.f;
  for (int d = 0; d < 256; d++)
    acc += Wv[((size_t)(g*256 + d))*256 + tid] * wa[d];
  wve[g*256 + tid] = acc;
  if (tid == 0){
    float s = 0.f;
    for (int d = 0; d < 256; d++) s += bvq[g*256 + d]*wa[d];
    bve[g] = s;
  }
}

// ---------------- persistent recurrent loop
__global__ __launch_bounds__(512, 2)
void k_loop(const float* __restrict__ gx, const float* __restrict__ Wh,
            const __half* __restrict__ wkh, const float* __restrict__ bkb,
            const float* __restrict__ wve, const float* __restrict__ bve,
            const __half* __restrict__ Qh, const float* __restrict__ bao,
            const float* __restrict__ Wout, const float* __restrict__ bout,
            float* __restrict__ c, float* __restrict__ og, float* __restrict__ vw,
            __half* __restrict__ Kth, float* __restrict__ stats, float* __restrict__ hH,
            float* __restrict__ y, unsigned* __restrict__ bar){
  __shared__ float S[25088];
  const int blk = blockIdx.x, tid = threadIdx.x;
  unsigned ph = 0;
  const float bao0 = bao[0];

  const int p1_b = blk >> 5, p1_s = blk & 31;
  const int gid  = blk;
  const int p3_b = blk >> 5, p3_ht = (blk >> 2) & 7, p3_gt = blk & 3;
  const int p3_h0 = p3_ht*32, p3_g0 = p3_gt*64;

  // hoist Wh fragment for P1
  float4 whr[4];
  int p1_row;
  {
    const int j = tid >> 4, part = tid & 15;
    const int rr = p1_s*32 + j, o = rr >> 2, gate = rr & 3;
    p1_row = gate*256 + o;
    const float4* wr = (const float4*)(Wh + (size_t)p1_row*256);
    #pragma unroll
    for (int u = 0; u < 4; u++) whr[u] = wr[u*16 + part];
  }

  for (int t = 0; t < 64; t++){
    // ---------- P1 ----------
    if (t > 0){
      if (tid < 256){
        const float* sp = stats + ((size_t)p1_b*256 + tid)*16;
        float2 a0 = cld2(sp+0);  float2 b0 = cld2(sp+2);
        float2 a1 = cld2(sp+4);  float2 b1 = cld2(sp+6);
        float2 a2 = cld2(sp+8);  float2 b2 = cld2(sp+10);
        float2 a3 = cld2(sp+12); float2 b3 = cld2(sp+14);
        float m = fmaxf(fmaxf(a0.x, a1.x), fmaxf(a2.x, a3.x));
        float e0 = expf(a0.x - m), e1 = expf(a1.x - m), e2 = expf(a2.x - m), e3 = expf(a3.x - m);
        float den = a0.y*e0 + a1.y*e1 + a2.y*e2 + a3.y*e3;
        float num = b0.x*e0 + b1.x*e1 + b2.x*e2 + b3.x*e3;
        float hv = num/den + bao0;
        S[tid] = hv;
        if (p1_s == 0) cst(&hH[(size_t)t*2048 + p1_b*256 + tid], hv);
      }
    } else {
      if (tid < 256) S[tid] = 0.f;
    }
    __syncthreads();
    {
      const int j = tid >> 4, part = tid & 15;
      const float4* h4 = (const float4*)S;
      float a0 = 0.f;
      #pragma unroll
      for (int u = 0; u < 4; u++)
        a0 += dot4(whr[u], h4[u*16 + part]);
      a0 += __shfl_xor(a0, 1);
      a0 += __shfl_xor(a0, 2);
      a0 += __shfl_xor(a0, 4);
      a0 += __shfl_xor(a0, 8);
      if (part == 0) S[256 + j] = a0 + gx[(size_t)(t*8 + p1_b)*1024 + p1_row];
    }
    __syncthreads();
    if (tid < 8){
      const int o_ = p1_s*8 + tid, ci = p1_b*256 + o_;
      float ig = sigmf(S[256 + tid*4 + 0]);
      float fg = sigmf(S[256 + tid*4 + 1]);
      float gg = tanhf(S[256 + tid*4 + 2]);
      float ov = sigmf(S[256 + tid*4 + 3]);
      float cv = cld(&c[ci]);
      cst(&c[ci], fg*cv + ig*gg);
      cst(&og[ci], ov);
    }
    gbar(bar, ++ph);

    // ---------- P2: K[:, g=gid, :] = Wk16 . c (fp16 out, R10 access pattern) ; vw[:, gid] ----------
    {
      int bb0 = tid >> 6, j40 = tid & 63;
      float* dst = &S[bb0*260 + j40*4];
      const float* src = &c[bb0*256 + j40*4];
      float2 v0 = cld2(src);
      float2 v1 = cld2(src+2);
      dst[0] = v0.x; dst[1] = v0.y; dst[2] = v1.x; dst[3] = v1.y;
    }
    __syncthreads();
    if (tid < 64){
      const int bb = tid >> 3, part = tid & 7;
      const float4* wv4 = (const float4*)(wve + gid*256);
      float sacc = 0.f;
      #pragma unroll
      for (int u = 0; u < 8; u++){
        float4 w = wv4[part*8 + u];
        const float* op = &og[bb*256 + (part*8 + u)*4];
        float2 o0 = cld2(op);
        float2 o1 = cld2(op+2);
        sacc += w.x*o0.x + w.y*o0.y + w.z*o1.x + w.w*o1.y;
      }
      sacc += __shfl_xor(sacc, 1);
      sacc += __shfl_xor(sacc, 2);
      sacc += __shfl_xor(sacc, 4);
      if (part == 0) cst(&vw[bb*256 + gid], sacc + bve[gid]);
    }
    {
      const float4* cl4 = (const float4*)S;
      #pragma unroll 2
      for (int p = 0; p < 8; p++){
        const int d = p*32 + (tid >> 4), part = tid & 15;
        const __half* wr = wkh + ((size_t)gid*256 + d)*256;
        float4 w0 = h4_to_f4(*(const uint2*)(wr + part*4));
        float4 w1 = h4_to_f4(*(const uint2*)(wr + 64 + part*4));
        float4 w2 = h4_to_f4(*(const uint2*)(wr + 128 + part*4));
        float4 w3 = h4_to_f4(*(const uint2*)(wr + 192 + part*4));
        float acc[8];
        #pragma unroll
        for (int bb = 0; bb < 8; bb++){
          acc[bb] = dot4(w0, cl4[bb*65 + part]) + dot4(w1, cl4[bb*65 + 16 + part])
                  + dot4(w2, cl4[bb*65 + 32 + part]) + dot4(w3, cl4[bb*65 + 48 + part]);
        }
        const float bkv = bkb[gid*256 + d];
        #pragma unroll
        for (int bb = 0; bb < 8; bb++){
          acc[bb] += __shfl_xor(acc[bb], 1);
          acc[bb] += __shfl_xor(acc[bb], 2);
          acc[bb] += __shfl_xor(acc[bb], 4);
          acc[bb] += __shfl_xor(acc[bb], 8);
          // full sum now in all 16 lanes of the group; pair d (even) with d+1 via xor-16
          float v = acc[bb] + bkv;
          float vo = __shfl_xor(v, 16);
          if ((((tid >> 4) & 1) == 0) && part == bb){
            __half2 hv = __floats2half2_rn(v, vo);
            csth2((unsigned*)&Kth[(size_t)bb*65536 + gid*256 + d], *(unsigned*)&hv);
          }
        }
      }
    }
    gbar(bar, ++ph);

    // ---------- P3: partial attention stats for (b, 32h, 64g) ----------
    {
      const __half* Qb = Qh + ((size_t)(t*8 + p3_b))*65536 + (size_t)p3_h0*256;
      #pragma unroll
      for (int i = 0; i < 2; i++){
        int f8 = i*512 + tid;
        int hh = f8 >> 5, j8 = f8 & 31;
        uint4 v = *(const uint4*)(Qb + hh*256 + j8*8);
        float4 a, b;
        h8_to_f8(v, a, b);
        float* dst = &S[hh*260 + j8*8];
        *(float4*)dst = a;
        *(float4*)(dst+4) = b;
      }
      const __half* Kbh = Kth + (size_t)p3_b*65536 + (size_t)p3_g0*256;
      float* Kl = S + 8320;
      #pragma unroll
      for (int i = 0; i < 8; i++){
        int f = i*512 + tid;
        int gg = f >> 6, c4i = f & 63;
        float4 v = cldh4(Kbh + gg*256 + c4i*4);
        *(float4*)&Kl[gg*260 + c4i*4] = v;
      }
      if (tid < 64) S[24960 + tid] = cld(&vw[p3_b*256 + p3_g0 + tid]);
      __syncthreads();
      const int kh = tid >> 7, r = tid & 127, ty = r >> 4, txl = r & 15;
      float acc[4][4];
      #pragma unroll
      for (int a = 0; a < 4; a++)
        #pragma unroll
        for (int i = 0; i < 4; i++) acc[a][i] = 0.f;
      const float4* Ql4 = (const float4*)S;
      const float4* Kl4 = (const float4*)(S + 8320);
      for (int k4 = 0; k4 < 16; k4++){
        const int kk = kh*16 + k4;
        float4 qv[4], kv[4];
        #pragma unroll
        for (int a = 0; a < 4; a++) qv[a] = Ql4[(ty + 8*a)*65 + kk];
        #pragma unroll
        for (int i = 0; i < 4; i++) kv[i] = Kl4[(txl + 16*i)*65 + kk];
        #pragma unroll
        for (int a = 0; a < 4; a++)
          #pragma unroll
          for (int i = 0; i < 4; i++)
            acc[a][i] += dot4(qv[a], kv[i]);
      }
      __syncthreads();
      float* Pl = S;
      if (kh > 0){
        #pragma unroll
        for (int a = 0; a < 4; a++)
          #pragma unroll
          for (int i = 0; i < 4; i++)
            Pl[(kh-1)*2048 + r*16 + a*4 + i] = acc[a][i];
      }
      __syncthreads();
      if (kh == 0){
        #pragma unroll
        for (int p = 0; p < 3; p++)
          #pragma unroll
          for (int a = 0; a < 4; a++)
            #pragma unroll
            for (int i = 0; i < 4; i++)
              acc[a][i] += Pl[p*2048 + r*16 + a*4 + i];
        #pragma unroll
        for (int a = 0; a < 4; a++)
          #pragma unroll
          for (int i = 0; i < 4; i++)
            acc[a][i] *= 0.0625f;
        #pragma unroll
        for (int a = 0; a < 4; a++){
          float mx = fmaxf(fmaxf(acc[a][0], acc[a][1]), fmaxf(acc[a][2], acc[a][3]));
          mx = fmaxf(mx, __shfl_xor(mx, 1));
          mx = fmaxf(mx, __shfl_xor(mx, 2));
          mx = fmaxf(mx, __shfl_xor(mx, 4));
          mx = fmaxf(mx, __shfl_xor(mx, 8));
          float den = 0.f, num = 0.f;
          #pragma unroll
          for (int i = 0; i < 4; i++){
            float pv = expf(acc[a][i] - mx);
            den += pv;
            num += pv * S[24960 + txl + 16*i];
          }
          den += __shfl_xor(den, 1); num += __shfl_xor(num, 1);
          den += __shfl_xor(den, 2); num += __shfl_xor(num, 2);
          den += __shfl_xor(den, 4); num += __shfl_xor(num, 4);
          den += __shfl_xor(den, 8); num += __shfl_xor(num, 8);
          if (txl == 0){
            const int h = p3_h0 + ty + 8*a;
            float* sp = &stats[(((size_t)p3_b*256 + h)*4 + p3_gt)*4];
            cst2(sp, mx, den);
            cst(sp+2, num);
          }
        }
      }
    }
    gbar(bar, ++ph);
  }

  // ---------- tail ----------
  if (p1_s == 0 && tid < 256){
    const float* sp = stats + ((size_t)p1_b*256 + tid)*16;
    float2 a0 = cld2(sp+0);  float2 b0 = cld2(sp+2);
    float2 a1 = cld2(sp+4);  float2 b1 = cld2(sp+6);
    float2 a2 = cld2(sp+8);  float2 b2 = cld2(sp+10);
    float2 a3 = cld2(sp+12); float2 b3 = cld2(sp+14);
    float m = fmaxf(fmaxf(a0.x, a1.x), fmaxf(a2.x, a3.x));
    float e0 = expf(a0.x - m), e1 = expf(a1.x - m), e2 = expf(a2.x - m), e3 = expf(a3.x - m);
    float den = a0.y*e0 + a1.y*e1 + a2.y*e2 + a3.y*e3;
    float num = b0.x*e0 + b1.x*e1 + b2.x*e2 + b3.x*e3;
    cst(&hH[(size_t)64*2048 + p1_b*256 + tid], num/den + bao0);
  }
  gbar(bar, ++ph);
  if (blk < 64 && tid < 80){
    const int t2 = blk;
    const int bb2 = tid/10, cc = tid - bb2*10;
    const float* hr = &hH[(size_t)(t2+1)*2048 + bb2*256];
    const float* wr2 = &Wout[cc*256];
    float acc = 0.f;
    for (int u = 0; u < 128; u++){
      float2 h2 = cld2(hr + u*2);
      acc += h2.x*wr2[u*2] + h2.y*wr2[u*2+1];
    }
    y[bb2*640 + cc*64 + t2] = acc + bout[cc];
  }
}

extern "C" void kernel_launch(void* const* d_in, const int* in_sizes, int n_in,
                              void* d_out, int out_size, void* d_ws, size_t ws_size,
                              hipStream_t stream){
  (void)in_sizes; (void)n_in; (void)out_size; (void)ws_size;
  const float* x      = (const float*)d_in[0];
  const float* w_init = (const float*)d_in[1];
  const float* b_init = (const float*)d_in[2];
  const float* c1w    = (const float*)d_in[3];
  const float* c1b    = (const float*)d_in[4];
  const float* c2w    = (const float*)d_in[5];
  const float* c2b    = (const float*)d_in[6];
  const float* c3w    = (const float*)d_in[7];
  const float* c3b    = (const float*)d_in[8];
  const float* Wx     = (const float*)d_in[9];
  const float* bx     = (const float*)d_in[10];
  const float* Wh     = (const float*)d_in[11];
  const float* bh     = (const float*)d_in[12];
  const float* Wxo    = (const float*)d_in[13];
  const float* bxo    = (const float*)d_in[14];
  const float* Wq     = (const float*)d_in[15];
  const float* bq     = (const float*)d_in[16];
  const float* Wk     = (const float*)d_in[17];
  const float* bk_    = (const float*)d_in[18];
  const float* Wv     = (const float*)d_in[19];
  const float* bv     = (const float*)d_in[20];
  const float* Wao    = (const float*)d_in[21];
  const float* bao    = (const float*)d_in[22];
  const float* Wout   = (const float*)d_in[23];
  const float* bout   = (const float*)d_in[24];
  float* y  = (float*)d_out;
  float* ws = (float*)d_ws;

  float* xin   = ws + WS_XIN;
  float* gf    = ws + WS_GF;
  float* stats = ws + WS_STATS;
  unsigned* bar = (unsigned*)(ws + WS_BARS);
  float* fs    = ws + WS_FS;
  float* xo    = ws + WS_XO;
  float* gxp   = ws + WS_GX;
  __half* Qh   = (__half*)(ws + WS_Q);
  __half* wkh  = (__half*)(ws + WS_WKH);
  float* wve   = ws + WS_WVE;
  float* bve   = ws + WS_BVE;
  __half* Kth  = (__half*)(ws + WS_KT);
  float* hH    = ws + WS_HH;
  float* cp    = ws + WS_C;
  float* ogp   = ws + WS_OG;
  float* vwp   = ws + WS_VW;

  k_init<<<256, 256, 0, stream>>>(x, ws);
  k_wk16<<<8192, 256, 0, stream>>>(Wk, wkh);
  k_gemm_nt<<<dim3(8, 4), 256, 0, stream>>>(w_init, xin, b_init, nullptr, gf, 1024, 128, 1);
  k_feconv<<<512, 256, 0, stream>>>(gf, c1w, c1b, c2w, c2b, c3w, c3b, fs);
  k_gemm_nt<<<dim3(2, 4), 256, 0, stream>>>(Wxo, fs, bxo, nullptr, xo, 256, 256, 2);
  k_gemm_nt<<<dim3(8, 4), 256, 0, stream>>>(Wx, fs, bx, bh, gxp, 1024, 256, 0);
  k_wveff<<<256, 256, 0, stream>>>(Wv, bv, Wao, wve, bve, bar);
  k_gemm_nt<<<dim3(512, 4), 256, 0, stream>>>(Wq, xo, bq, nullptr, (float*)Qh, 65536, 256, 3);
  k_loop<<<NBLK, 512, 0, stream>>>(gxp, Wh, wkh, bk_, wve, bve, Qh, bao, Wout, bout,
                                   cp, ogp, vwp, Kth, stats, hH, y, bar);
}

// Round 13
// 2570.879 us; speedup vs baseline: 1.7452x; 1.1050x over previous
//
#include <hip/hip_runtime.h>
#include <hip/hip_fp16.h>
#include <math.h>

// Workspace layout (float offsets)
#define WS_XIN   0L
#define WS_GF    65536L
#define WS_STATS 65536L      // [8][256][4][4] softmax partials
#define WS_BARS  98304L      // barrier region: 8192 unsigned words
#define WS_FS    589824L
#define WS_XO    720896L
#define WS_GX    851968L
#define WS_Q     1376256L    // fp16 [512][65536]
#define WS_WKH   18153472L   // fp16 [65536][256]
#define WS_WVE   34930688L
#define WS_BVE   34996224L
#define WS_KT    34996480L   // fp32 Kt[b][g][d]
#define WS_HH    35520768L   // [65][2048]
#define WS_C     35653888L
#define WS_OG    35655936L
#define WS_VW    35657984L

#define NBLK 256

typedef unsigned long long u64;

__device__ __forceinline__ float sigmf(float x){ return 1.0f/(1.0f + expf(-x)); }
__device__ __forceinline__ float dot4(float4 a, float4 b){
  return a.x*b.x + a.y*b.y + a.z*b.z + a.w*b.w;
}
__device__ __forceinline__ void h8_to_f8(uint4 v, float4& a, float4& b){
  const __half2* hp = (const __half2*)&v;
  float2 f0 = __half22float2(hp[0]);
  float2 f1 = __half22float2(hp[1]);
  float2 f2 = __half22float2(hp[2]);
  float2 f3 = __half22float2(hp[3]);
  a = make_float4(f0.x, f0.y, f1.x, f1.y);
  b = make_float4(f2.x, f2.y, f3.x, f3.y);
}
__device__ __forceinline__ float4 h4_to_f4(uint2 v){
  const __half2* hp = (const __half2*)&v;
  float2 f0 = __half22float2(hp[0]);
  float2 f1 = __half22float2(hp[1]);
  return make_float4(f0.x, f0.y, f1.x, f1.y);
}

// coherent (device-point) accesses for cross-block mutable data — AGENT scope
__device__ __forceinline__ float cld(const float* p){
  return __hip_atomic_load((float*)p, __ATOMIC_RELAXED, __HIP_MEMORY_SCOPE_AGENT);
}
__device__ __forceinline__ void cst(float* p, float v){
  __hip_atomic_store(p, v, __ATOMIC_RELAXED, __HIP_MEMORY_SCOPE_AGENT);
}
__device__ __forceinline__ float2 cld2(const float* p){
  u64 v = __hip_atomic_load((const u64*)p, __ATOMIC_RELAXED, __HIP_MEMORY_SCOPE_AGENT);
  float2 r;
  r.x = __uint_as_float((unsigned)(v & 0xffffffffu));
  r.y = __uint_as_float((unsigned)(v >> 32));
  return r;
}
__device__ __forceinline__ void cst2(float* p, float a, float b){
  u64 v = ((u64)__float_as_uint(b) << 32) | (u64)__float_as_uint(a);
  __hip_atomic_store((u64*)p, v, __ATOMIC_RELAXED, __HIP_MEMORY_SCOPE_AGENT);
}

// hierarchical grid barrier: 32 groups x 8 blocks, monotonic phase counters.
__device__ __forceinline__ void gbar(unsigned* bar, unsigned ph){
  __syncthreads();
  if (threadIdx.x == 0){
    const unsigned g = blockIdx.x & 31u;
    asm volatile("s_waitcnt vmcnt(0)" ::: "memory");
    unsigned old = __hip_atomic_fetch_add(&bar[g*64], 1u, __ATOMIC_RELAXED, __HIP_MEMORY_SCOPE_AGENT);
    if (old == ph*8u - 1u){
      unsigned t = __hip_atomic_fetch_add(&bar[2048], 1u, __ATOMIC_RELAXED, __HIP_MEMORY_SCOPE_AGENT);
      if (t == ph*32u - 1u)
        __hip_atomic_store(&bar[2112], ph, __ATOMIC_RELAXED, __HIP_MEMORY_SCOPE_AGENT);
    }
    if (blockIdx.x < 32){
      while (__hip_atomic_load(&bar[2112], __ATOMIC_RELAXED, __HIP_MEMORY_SCOPE_AGENT) < ph)
        __builtin_amdgcn_s_sleep(2);
      __hip_atomic_store(&bar[2176 + blockIdx.x*64], ph, __ATOMIC_RELAXED, __HIP_MEMORY_SCOPE_AGENT);
    } else {
      while (__hip_atomic_load(&bar[2176 + g*64], __ATOMIC_RELAXED, __HIP_MEMORY_SCOPE_AGENT) < ph)
        __builtin_amdgcn_s_sleep(2);
    }
  }
  __syncthreads();
}

// ---------------- init
__launch_bounds__(256)
__global__ void k_init(const float* __restrict__ x, float* __restrict__ ws){
  int i = blockIdx.x*256 + threadIdx.x;
  int r = i >> 7, m = i & 127;
  int t = r >> 3, b = r & 7;
  ws[WS_XIN + i] = x[b*8192 + m*64 + t];
  if (i < 2048){ ws[WS_HH + i] = 0.f; ws[WS_C + i] = 0.f; }
}

// ---------------- Wk -> fp16
__launch_bounds__(256)
__global__ void k_wk16(const float* __restrict__ in, __half* __restrict__ out){
  size_t i = ((size_t)blockIdx.x*256 + threadIdx.x)*8;
  float4 a = *(const float4*)(in + i);
  float4 b = *(const float4*)(in + i + 4);
  uint4 v;
  __half2* vp = (__half2*)&v;
  vp[0] = __floats2half2_rn(a.x, a.y);
  vp[1] = __floats2half2_rn(a.z, a.w);
  vp[2] = __floats2half2_rn(b.x, b.y);
  vp[3] = __floats2half2_rn(b.z, b.w);
  *(uint4*)(out + i) = v;
}

// ---------------- generic GEMM (act: 0 none, 1 relu, 2 sigmoid, 3 none+fp16 out)
__launch_bounds__(256)
__global__ void k_gemm_nt(const float* __restrict__ W, const float* __restrict__ X,
                          const float* __restrict__ b1, const float* __restrict__ b2,
                          float* __restrict__ out, int M, int K, int act){
  __shared__ float Wt[32*132];
  __shared__ float Xt[32*132];
  const int tid = threadIdx.x;
  const int tx = tid & 15, ty = tid >> 4;
  const int m0 = blockIdx.x * 128, n0 = blockIdx.y * 128;
  float acc[8][8];
  #pragma unroll
  for (int i = 0; i < 8; i++)
    #pragma unroll
    for (int j = 0; j < 8; j++) acc[i][j] = 0.f;

  for (int k0 = 0; k0 < K; k0 += 32){
    #pragma unroll
    for (int i = 0; i < 4; i++){
      int f4 = i*256 + tid;
      int row = f4 >> 3;
      int j4 = (f4 & 7) * 4;
      float4 w = *(const float4*)&W[(size_t)(m0+row)*K + k0 + j4];
      Wt[(j4+0)*132 + row] = w.x;
      Wt[(j4+1)*132 + row] = w.y;
      Wt[(j4+2)*132 + row] = w.z;
      Wt[(j4+3)*132 + row] = w.w;
      float4 xv = *(const float4*)&X[(size_t)(n0+row)*K + k0 + j4];
      Xt[(j4+0)*132 + row] = xv.x;
      Xt[(j4+1)*132 + row] = xv.y;
      Xt[(j4+2)*132 + row] = xv.z;
      Xt[(j4+3)*132 + row] = xv.w;
    }
    __syncthreads();
    for (int k = 0; k < 32; k++){
      float4 a0 = *(const float4*)&Wt[k*132 + 4*tx];
      float4 a1 = *(const float4*)&Wt[k*132 + 64 + 4*tx];
      float4 x0 = *(const float4*)&Xt[k*132 + 4*ty];
      float4 x1 = *(const float4*)&Xt[k*132 + 64 + 4*ty];
      float am[8] = {a0.x,a0.y,a0.z,a0.w,a1.x,a1.y,a1.z,a1.w};
      float xn[8] = {x0.x,x0.y,x0.z,x0.w,x1.x,x1.y,x1.z,x1.w};
      #pragma unroll
      for (int mi = 0; mi < 8; mi++)
        #pragma unroll
        for (int ni = 0; ni < 8; ni++)
          acc[mi][ni] += am[mi]*xn[ni];
    }
    __syncthreads();
  }

  float bvv[8];
  #pragma unroll
  for (int mi = 0; mi < 8; mi++){
    int m = m0 + ((mi < 4) ? (4*tx + mi) : (64 + 4*tx + mi - 4));
    float bb = b1[m];
    if (b2) bb += b2[m];
    bvv[mi] = bb;
  }
  #pragma unroll
  for (int ni = 0; ni < 8; ni++){
    int n = n0 + ((ni < 4) ? (4*ty + ni) : (64 + 4*ty + ni - 4));
    float v[8];
    #pragma unroll
    for (int mi = 0; mi < 8; mi++){
      float q = acc[mi][ni] + bvv[mi];
      if (act == 1) q = fmaxf(q, 0.f);
      else if (act == 2) q = 1.0f/(1.0f + expf(-q));
      v[mi] = q;
    }
    if (act == 3){
      __half* outh = (__half*)out;
      uint2 u0, u1;
      __half2* up0 = (__half2*)&u0;
      __half2* up1 = (__half2*)&u1;
      up0[0] = __floats2half2_rn(v[0], v[1]);
      up0[1] = __floats2half2_rn(v[2], v[3]);
      up1[0] = __floats2half2_rn(v[4], v[5]);
      up1[1] = __floats2half2_rn(v[6], v[7]);
      *(uint2*)&outh[(size_t)n*M + m0 + 4*tx]      = u0;
      *(uint2*)&outh[(size_t)n*M + m0 + 64 + 4*tx] = u1;
    } else {
      *(float4*)&out[(size_t)n*M + m0 + 4*tx]      = make_float4(v[0],v[1],v[2],v[3]);
      *(float4*)&out[(size_t)n*M + m0 + 64 + 4*tx] = make_float4(v[4],v[5],v[6],v[7]);
    }
  }
}

// ---------------- feature extractor conv chain
__launch_bounds__(256)
__global__ void k_feconv(const float* __restrict__ gf, const float* __restrict__ c1w,
                         const float* __restrict__ c1b, const float* __restrict__ c2w,
                         const float* __restrict__ c2b, const float* __restrict__ c3w,
                         const float* __restrict__ c3b, float* __restrict__ fs){
  __shared__ float fc[1024];
  __shared__ float p1[16*512];
  __shared__ float p2[32*256];
  __shared__ float w1[48], w2[1536], w3[96], bb1[16], bb2[32];
  const int r = blockIdx.x, tid = threadIdx.x;
  #pragma unroll
  for (int i = 0; i < 4; i++) fc[i*256 + tid] = gf[(size_t)r*1024 + i*256 + tid];
  if (tid < 48) w1[tid] = c1w[tid];
  if (tid < 16) bb1[tid] = c1b[tid];
  for (int i = tid; i < 1536; i += 256) w2[i] = c2w[i];
  if (tid < 32) bb2[tid] = c2b[tid];
  if (tid < 96) w3[tid] = c3w[tid];
  __syncthreads();
  for (int i = 0; i < 32; i++){
    int idx = i*256 + tid;
    int ch = idx >> 9, p = idx & 511;
    float k0 = w1[ch*3], k1 = w1[ch*3+1], k2 = w1[ch*3+2], bias = bb1[ch];
    int q = 2*p;
    float xm1 = (q >= 1) ? fc[q-1] : 0.f;
    float x0 = fc[q];
    float x1 = fc[q+1];
    float x2 = (q+2 < 1024) ? fc[q+2] : 0.f;
    float a0 = bias + k0*xm1 + k1*x0 + k2*x1;
    float a1 = bias + k0*x0 + k1*x1 + k2*x2;
    p1[ch*512 + p] = fmaxf(fmaxf(a0, 0.f), fmaxf(a1, 0.f));
  }
  __syncthreads();
  for (int i = 0; i < 32; i++){
    int idx = i*256 + tid;
    int ch = idx >> 8, p = idx & 255;
    float a0 = bb2[ch], a1 = bb2[ch];
    int q = 2*p;
    #pragma unroll
    for (int ci = 0; ci < 16; ci++){
      const float* wp = &w2[(ch*16+ci)*3];
      const float* ip = &p1[ci*512];
      float xm1 = (q >= 1) ? ip[q-1] : 0.f;
      float x0 = ip[q];
      float x1 = ip[q+1];
      float x2 = (q+2 < 512) ? ip[q+2] : 0.f;
      a0 += wp[0]*xm1 + wp[1]*x0 + wp[2]*x1;
      a1 += wp[0]*x0  + wp[1]*x1 + wp[2]*x2;
    }
    p2[ch*256 + p] = fmaxf(fmaxf(a0, 0.f), fmaxf(a1, 0.f));
  }
  __syncthreads();
  if (tid < 256){
    float a = c3b[0];
    const int l = tid;
    #pragma unroll
    for (int ci = 0; ci < 32; ci++){
      const float* wp = &w3[ci*3];
      const float* ip = &p2[ci*256];
      float xm1 = (l >= 1) ? ip[l-1] : 0.f;
      float x0 = ip[l];
      float x2 = (l+1 < 256) ? ip[l+1] : 0.f;
      a += wp[0]*xm1 + wp[1]*x0 + wp[2]*x2;
    }
    fs[(size_t)r*256 + l] = a;
  }
}

// ---------------- Wv_eff + barrier region init
__launch_bounds__(256)
__global__ void k_wveff(const float* __restrict__ Wv, const float* __restrict__ bvq,
                        const float* __restrict__ Wao, float* __restrict__ wve,
                        float* __restrict__ bve, unsigned* __restrict__ bar){
  __shared__ float wa[256];
  const int g = blockIdx.x, tid = threadIdx.x;
  if (g == 0){
    for (int i = tid; i < 8192; i += 256) bar[i] = 0u;
  }
  wa[tid] = Wao[tid];
  __syncthreads();
  float acc = 0.f;
  for (int d = 0; d < 256; d++)
    acc += Wv[((size_t)(g*256 + d))*256 + tid] * wa[d];
  wve[g*256 + tid] = acc;
  if (tid == 0){
    float s = 0.f;
    for (int d = 0; d < 256; d++) s += bvq[g*256 + d]*wa[d];
    bve[g] = s;
  }
}

// ---------------- persistent recurrent loop
__global__ __launch_bounds__(512, 2)
void k_loop(const float* __restrict__ gx, const float* __restrict__ Wh,
            const __half* __restrict__ wkh, const float* __restrict__ bkb,
            const float* __restrict__ wve, const float* __restrict__ bve,
            const __half* __restrict__ Qh, const float* __restrict__ bao,
            const float* __restrict__ Wout, const float* __restrict__ bout,
            float* __restrict__ c, float* __restrict__ og, float* __restrict__ vw,
            float* __restrict__ Kt, float* __restrict__ stats, float* __restrict__ hH,
            float* __restrict__ y, unsigned* __restrict__ bar){
  __shared__ float S[25088];
  // LDS map: P1 uses [0,288); P2 cl [0,2080);
  // P3: Pl [0,6144), Kl [8320,16640), Ql [16640,24960), vwl [24960,25024)
  const int blk = blockIdx.x, tid = threadIdx.x;
  unsigned ph = 0;
  const float bao0 = bao[0];

  const int p1_b = blk >> 5, p1_s = blk & 31;
  const int gid  = blk;
  const int p3_b = blk >> 5, p3_ht = (blk >> 2) & 7, p3_gt = blk & 3;
  const int p3_h0 = p3_ht*32, p3_g0 = p3_gt*64;

  // hoist Wh fragment for P1
  float4 whr[4];
  int p1_row;
  {
    const int j = tid >> 4, part = tid & 15;
    const int rr = p1_s*32 + j, o = rr >> 2, gate = rr & 3;
    p1_row = gate*256 + o;
    const float4* wr = (const float4*)(Wh + (size_t)p1_row*256);
    #pragma unroll
    for (int u = 0; u < 4; u++) whr[u] = wr[u*16 + part];
  }

  // Q prefetch geometry (per thread: 2 chunks of 8 halves)
  const int qf0 = tid, qf1 = 512 + tid;
  const int qhh0 = qf0 >> 5, qj0 = qf0 & 31;
  const int qhh1 = qf1 >> 5, qj1 = qf1 & 31;

  typedef unsigned uint4v __attribute__((ext_vector_type(4)));

  for (int t = 0; t < 64; t++){
    // ---------- Q prefetch (registers; latency hidden under P1+P2) ----------
    const __half* Qb = Qh + ((size_t)(t*8 + p3_b))*65536 + (size_t)p3_h0*256;
    uint4v qv0 = __builtin_nontemporal_load((const uint4v*)(Qb + qhh0*256 + qj0*8));
    uint4v qv1 = __builtin_nontemporal_load((const uint4v*)(Qb + qhh1*256 + qj1*8));

    // ---------- P1 ----------
    if (t > 0){
      if (tid < 256){
        const float* sp = stats + ((size_t)p1_b*256 + tid)*16;
        float2 a0 = cld2(sp+0);  float2 b0 = cld2(sp+2);
        float2 a1 = cld2(sp+4);  float2 b1 = cld2(sp+6);
        float2 a2 = cld2(sp+8);  float2 b2 = cld2(sp+10);
        float2 a3 = cld2(sp+12); float2 b3 = cld2(sp+14);
        float m = fmaxf(fmaxf(a0.x, a1.x), fmaxf(a2.x, a3.x));
        float e0 = expf(a0.x - m), e1 = expf(a1.x - m), e2 = expf(a2.x - m), e3 = expf(a3.x - m);
        float den = a0.y*e0 + a1.y*e1 + a2.y*e2 + a3.y*e3;
        float num = b0.x*e0 + b1.x*e1 + b2.x*e2 + b3.x*e3;
        float hv = num/den + bao0;
        S[tid] = hv;
        if (p1_s == 0) cst(&hH[(size_t)t*2048 + p1_b*256 + tid], hv);
      }
    } else {
      if (tid < 256) S[tid] = 0.f;
    }
    __syncthreads();
    {
      const int j = tid >> 4, part = tid & 15;
      const float4* h4 = (const float4*)S;
      float a0 = 0.f;
      #pragma unroll
      for (int u = 0; u < 4; u++)
        a0 += dot4(whr[u], h4[u*16 + part]);
      a0 += __shfl_xor(a0, 1);
      a0 += __shfl_xor(a0, 2);
      a0 += __shfl_xor(a0, 4);
      a0 += __shfl_xor(a0, 8);
      if (part == 0) S[256 + j] = a0 + gx[(size_t)(t*8 + p1_b)*1024 + p1_row];
    }
    __syncthreads();
    if (tid < 8){
      const int o_ = p1_s*8 + tid, ci = p1_b*256 + o_;
      float ig = sigmf(S[256 + tid*4 + 0]);
      float fg = sigmf(S[256 + tid*4 + 1]);
      float gg = tanhf(S[256 + tid*4 + 2]);
      float ov = sigmf(S[256 + tid*4 + 3]);
      float cv = cld(&c[ci]);
      cst(&c[ci], fg*cv + ig*gg);
      cst(&og[ci], ov);
    }
    gbar(bar, ++ph);

    // ---------- P2: K[:, g=gid, :] = Wk16 . c ; vw[:, gid] ----------
    {
      int bb0 = tid >> 6, j40 = tid & 63;
      float* dst = &S[bb0*260 + j40*4];
      const float* src = &c[bb0*256 + j40*4];
      float2 v0 = cld2(src);
      float2 v1 = cld2(src+2);
      dst[0] = v0.x; dst[1] = v0.y; dst[2] = v1.x; dst[3] = v1.y;
    }
    __syncthreads();
    if (tid < 64){
      const int bb = tid >> 3, part = tid & 7;
      const float4* wv4 = (const float4*)(wve + gid*256);
      float sacc = 0.f;
      #pragma unroll
      for (int u = 0; u < 8; u++){
        float4 w = wv4[part*8 + u];
        const float* op = &og[bb*256 + (part*8 + u)*4];
        float2 o0 = cld2(op);
        float2 o1 = cld2(op+2);
        sacc += w.x*o0.x + w.y*o0.y + w.z*o1.x + w.w*o1.y;
      }
      sacc += __shfl_xor(sacc, 1);
      sacc += __shfl_xor(sacc, 2);
      sacc += __shfl_xor(sacc, 4);
      if (part == 0) cst(&vw[bb*256 + gid], sacc + bve[gid]);
    }
    {
      const float4* cl4 = (const float4*)S;
      #pragma unroll 2
      for (int p = 0; p < 8; p++){
        const int d = p*32 + (tid >> 4), part = tid & 15;
        const __half* wr = wkh + ((size_t)gid*256 + d)*256;
        float4 w0 = h4_to_f4(*(const uint2*)(wr + part*4));
        float4 w1 = h4_to_f4(*(const uint2*)(wr + 64 + part*4));
        float4 w2 = h4_to_f4(*(const uint2*)(wr + 128 + part*4));
        float4 w3 = h4_to_f4(*(const uint2*)(wr + 192 + part*4));
        float acc[8];
        #pragma unroll
        for (int bb = 0; bb < 8; bb++){
          acc[bb] = dot4(w0, cl4[bb*65 + part]) + dot4(w1, cl4[bb*65 + 16 + part])
                  + dot4(w2, cl4[bb*65 + 32 + part]) + dot4(w3, cl4[bb*65 + 48 + part]);
        }
        #pragma unroll
        for (int bb = 0; bb < 8; bb++){
          acc[bb] += __shfl_xor(acc[bb], 1);
          acc[bb] += __shfl_xor(acc[bb], 2);
          acc[bb] += __shfl_xor(acc[bb], 4);
          acc[bb] += __shfl_xor(acc[bb], 8);
        }
        const float bkv = bkb[gid*256 + d];
        if (part < 8)
          cst(&Kt[(size_t)part*65536 + gid*256 + d], acc[part] + bkv);
      }
    }
    gbar(bar, ++ph);

    // ---------- P3: partial attention stats for (b, 32h, 64g) ----------
    {
      float* Ql = S + 16640;
      {
        uint4 v0 = *(uint4*)&qv0;
        float4 a, b;
        h8_to_f8(v0, a, b);
        float* dst = &Ql[qhh0*260 + qj0*8];
        *(float4*)dst = a;
        *(float4*)(dst+4) = b;
        uint4 v1 = *(uint4*)&qv1;
        h8_to_f8(v1, a, b);
        dst = &Ql[qhh1*260 + qj1*8];
        *(float4*)dst = a;
        *(float4*)(dst+4) = b;
      }
      const float* Kb = Kt + (size_t)p3_b*65536 + (size_t)p3_g0*256;
      float* Kl = S + 8320;
      #pragma unroll
      for (int i = 0; i < 8; i++){
        int f4 = i*512 + tid;
        int gg = f4 >> 6, j4 = (f4 & 63)*4;
        float* dst = &Kl[gg*260 + j4];
        const float* src = &Kb[gg*256 + j4];
        float2 v0 = cld2(src);
        float2 v1 = cld2(src+2);
        dst[0] = v0.x; dst[1] = v0.y; dst[2] = v1.x; dst[3] = v1.y;
      }
      if (tid < 64) S[24960 + tid] = cld(&vw[p3_b*256 + p3_g0 + tid]);
      __syncthreads();
      const int kh = tid >> 7, r = tid & 127, ty = r >> 4, txl = r & 15;
      float acc[4][4];
      #pragma unroll
      for (int a = 0; a < 4; a++)
        #pragma unroll
        for (int i = 0; i < 4; i++) acc[a][i] = 0.f;
      const float4* Ql4 = (const float4*)(S + 16640);
      const float4* Kl4 = (const float4*)(S + 8320);
      for (int k4 = 0; k4 < 16; k4++){
        const int kk = kh*16 + k4;
        float4 qv[4], kv[4];
        #pragma unroll
        for (int a = 0; a < 4; a++) qv[a] = Ql4[(ty + 8*a)*65 + kk];
        #pragma unroll
        for (int i = 0; i < 4; i++) kv[i] = Kl4[(txl + 16*i)*65 + kk];
        #pragma unroll
        for (int a = 0; a < 4; a++)
          #pragma unroll
          for (int i = 0; i < 4; i++)
            acc[a][i] += dot4(qv[a], kv[i]);
      }
      __syncthreads();
      float* Pl = S;
      if (kh > 0){
        #pragma unroll
        for (int a = 0; a < 4; a++)
          #pragma unroll
          for (int i = 0; i < 4; i++)
            Pl[(kh-1)*2048 + r*16 + a*4 + i] = acc[a][i];
      }
      __syncthreads();
      if (kh == 0){
        #pragma unroll
        for (int p = 0; p < 3; p++)
          #pragma unroll
          for (int a = 0; a < 4; a++)
            #pragma unroll
            for (int i = 0; i < 4; i++)
              acc[a][i] += Pl[p*2048 + r*16 + a*4 + i];
        #pragma unroll
        for (int a = 0; a < 4; a++)
          #pragma unroll
          for (int i = 0; i < 4; i++)
            acc[a][i] *= 0.0625f;
        #pragma unroll
        for (int a = 0; a < 4; a++){
          float mx = fmaxf(fmaxf(acc[a][0], acc[a][1]), fmaxf(acc[a][2], acc[a][3]));
          mx = fmaxf(mx, __shfl_xor(mx, 1));
          mx = fmaxf(mx, __shfl_xor(mx, 2));
          mx = fmaxf(mx, __shfl_xor(mx, 4));
          mx = fmaxf(mx, __shfl_xor(mx, 8));
          float den = 0.f, num = 0.f;
          #pragma unroll
          for (int i = 0; i < 4; i++){
            float pv = expf(acc[a][i] - mx);
            den += pv;
            num += pv * S[24960 + txl + 16*i];
          }
          den += __shfl_xor(den, 1); num += __shfl_xor(num, 1);
          den += __shfl_xor(den, 2); num += __shfl_xor(num, 2);
          den += __shfl_xor(den, 4); num += __shfl_xor(num, 4);
          den += __shfl_xor(den, 8); num += __shfl_xor(num, 8);
          if (txl == 0){
            const int h = p3_h0 + ty + 8*a;
            float* sp = &stats[(((size_t)p3_b*256 + h)*4 + p3_gt)*4];
            cst2(sp, mx, den);
            cst(sp+2, num);
          }
        }
      }
    }
    gbar(bar, ++ph);
  }

  // ---------- tail ----------
  if (p1_s == 0 && tid < 256){
    const float* sp = stats + ((size_t)p1_b*256 + tid)*16;
    float2 a0 = cld2(sp+0);  float2 b0 = cld2(sp+2);
    float2 a1 = cld2(sp+4);  float2 b1 = cld2(sp+6);
    float2 a2 = cld2(sp+8);  float2 b2 = cld2(sp+10);
    float2 a3 = cld2(sp+12); float2 b3 = cld2(sp+14);
    float m = fmaxf(fmaxf(a0.x, a1.x), fmaxf(a2.x, a3.x));
    float e0 = expf(a0.x - m), e1 = expf(a1.x - m), e2 = expf(a2.x - m), e3 = expf(a3.x - m);
    float den = a0.y*e0 + a1.y*e1 + a2.y*e2 + a3.y*e3;
    float num = b0.x*e0 + b1.x*e1 + b2.x*e2 + b3.x*e3;
    cst(&hH[(size_t)64*2048 + p1_b*256 + tid], num/den + bao0);
  }
  gbar(bar, ++ph);
  if (blk < 64 && tid < 80){
    const int t2 = blk;
    const int bb2 = tid/10, cc = tid - bb2*10;
    const float* hr = &hH[(size_t)(t2+1)*2048 + bb2*256];
    const float* wr2 = &Wout[cc*256];
    float acc = 0.f;
    for (int u = 0; u < 128; u++){
      float2 h2 = cld2(hr + u*2);
      acc += h2.x*wr2[u*2] + h2.y*wr2[u*2+1];
    }
    y[bb2*640 + cc*64 + t2] = acc + bout[cc];
  }
}

extern "C" void kernel_launch(void* const* d_in, const int* in_sizes, int n_in,
                              void* d_out, int out_size, void* d_ws, size_t ws_size,
                              hipStream_t stream){
  (void)in_sizes; (void)n_in; (void)out_size; (void)ws_size;
  const float* x      = (const float*)d_in[0];
  const float* w_init = (const float*)d_in[1];
  const float* b_init = (const float*)d_in[2];
  const float* c1w    = (const float*)d_in[3];
  const float* c1b    = (const float*)d_in[4];
  const float* c2w    = (const float*)d_in[5];
  const float* c2b    = (const float*)d_in[6];
  const float* c3w    = (const float*)d_in[7];
  const float* c3b    = (const float*)d_in[8];
  const float* Wx     = (const float*)d_in[9];
  const float* bx     = (const float*)d_in[10];
  const float* Wh     = (const float*)d_in[11];
  const float* bh     = (const float*)d_in[12];
  const float* Wxo    = (const float*)d_in[13];
  const float* bxo    = (const float*)d_in[14];
  const float* Wq     = (const float*)d_in[15];
  const float* bq     = (const float*)d_in[16];
  const float* Wk     = (const float*)d_in[17];
  const float* bk_    = (const float*)d_in[18];
  const float* Wv     = (const float*)d_in[19];
  const float* bv     = (const float*)d_in[20];
  const float* Wao    = (const float*)d_in[21];
  const float* bao    = (const float*)d_in[22];
  const float* Wout   = (const float*)d_in[23];
  const float* bout   = (const float*)d_in[24];
  float* y  = (float*)d_out;
  float* ws = (float*)d_ws;

  float* xin   = ws + WS_XIN;
  float* gf    = ws + WS_GF;
  float* stats = ws + WS_STATS;
  unsigned* bar = (unsigned*)(ws + WS_BARS);
  float* fs    = ws + WS_FS;
  float* xo    = ws + WS_XO;
  float* gxp   = ws + WS_GX;
  __half* Qh   = (__half*)(ws + WS_Q);
  __half* wkh  = (__half*)(ws + WS_WKH);
  float* wve   = ws + WS_WVE;
  float* bve   = ws + WS_BVE;
  float* Ktp   = ws + WS_KT;
  float* hH    = ws + WS_HH;
  float* cp    = ws + WS_C;
  float* ogp   = ws + WS_OG;
  float* vwp   = ws + WS_VW;

  k_init<<<256, 256, 0, stream>>>(x, ws);
  k_wk16<<<8192, 256, 0, stream>>>(Wk, wkh);
  k_gemm_nt<<<dim3(8, 4), 256, 0, stream>>>(w_init, xin, b_init, nullptr, gf, 1024, 128, 1);
  k_feconv<<<512, 256, 0, stream>>>(gf, c1w, c1b, c2w, c2b, c3w, c3b, fs);
  k_gemm_nt<<<dim3(2, 4), 256, 0, stream>>>(Wxo, fs, bxo, nullptr, xo, 256, 256, 2);
  k_gemm_nt<<<dim3(8, 4), 256, 0, stream>>>(Wx, fs, bx, bh, gxp, 1024, 256, 0);
  k_wveff<<<256, 256, 0, stream>>>(Wv, bv, Wao, wve, bve, bar);
  k_gemm_nt<<<dim3(512, 4), 256, 0, stream>>>(Wq, xo, bq, nullptr, (float*)Qh, 65536, 256, 3);
  k_loop<<<NBLK, 512, 0, stream>>>(gxp, Wh, wkh, bk_, wve, bve, Qh, bao, Wout, bout,
                                   cp, ogp, vwp, Ktp, stats, hH, y, bar);
}

// Round 14
// 2477.174 us; speedup vs baseline: 1.8112x; 1.0378x over previous
//
#include <hip/hip_runtime.h>
#include <hip/hip_fp16.h>
#include <math.h>

// Workspace layout (float offsets)
#define WS_XIN   0L
#define WS_GF    65536L
#define WS_STATS 65536L      // [8][256][4][4] softmax partials
#define WS_BARS  98304L      // barrier region: 8192 unsigned words
#define WS_FS    589824L
#define WS_XO    720896L
#define WS_GX    851968L
#define WS_Q     1376256L    // fp16 [512][65536]  -> ends 18153472
#define WS_WKH   18153472L   // fp16 [65536][256]  -> ends 26542080
#define WS_WQH   26542080L   // fp16 [65536][256]  -> ends 34930688
#define WS_WVE   34930688L
#define WS_BVE   34996224L
#define WS_KT    34996480L   // fp32 Kt[b][g][d]
#define WS_HH    35520768L   // [65][2048]
#define WS_C     35653888L
#define WS_OG    35655936L
#define WS_VW    35657984L

#define NBLK 256

typedef unsigned long long u64;
typedef _Float16 h2v __attribute__((ext_vector_type(2)));

__device__ __forceinline__ float sigmf(float x){ return 1.0f/(1.0f + expf(-x)); }
__device__ __forceinline__ float dot4(float4 a, float4 b){
  return a.x*b.x + a.y*b.y + a.z*b.z + a.w*b.w;
}
__device__ __forceinline__ void h8_to_f8(uint4 v, float4& a, float4& b){
  const __half2* hp = (const __half2*)&v;
  float2 f0 = __half22float2(hp[0]);
  float2 f1 = __half22float2(hp[1]);
  float2 f2 = __half22float2(hp[2]);
  float2 f3 = __half22float2(hp[3]);
  a = make_float4(f0.x, f0.y, f1.x, f1.y);
  b = make_float4(f2.x, f2.y, f3.x, f3.y);
}
__device__ __forceinline__ float4 h4_to_f4(uint2 v){
  const __half2* hp = (const __half2*)&v;
  float2 f0 = __half22float2(hp[0]);
  float2 f1 = __half22float2(hp[1]);
  return make_float4(f0.x, f0.y, f1.x, f1.y);
}
__device__ __forceinline__ float fdot2c(__half2 a, __half2 b, float c){
#if __has_builtin(__builtin_amdgcn_fdot2)
  h2v av = *(h2v*)&a;
  h2v bv = *(h2v*)&b;
  return __builtin_amdgcn_fdot2(av, bv, c, false);
#else
  float2 af = __half22float2(a);
  float2 bf = __half22float2(b);
  return fmaf(af.y, bf.y, fmaf(af.x, bf.x, c));
#endif
}

// coherent (device-point) accesses for cross-block mutable data — AGENT scope
__device__ __forceinline__ float cld(const float* p){
  return __hip_atomic_load((float*)p, __ATOMIC_RELAXED, __HIP_MEMORY_SCOPE_AGENT);
}
__device__ __forceinline__ void cst(float* p, float v){
  __hip_atomic_store(p, v, __ATOMIC_RELAXED, __HIP_MEMORY_SCOPE_AGENT);
}
__device__ __forceinline__ float2 cld2(const float* p){
  u64 v = __hip_atomic_load((const u64*)p, __ATOMIC_RELAXED, __HIP_MEMORY_SCOPE_AGENT);
  float2 r;
  r.x = __uint_as_float((unsigned)(v & 0xffffffffu));
  r.y = __uint_as_float((unsigned)(v >> 32));
  return r;
}
__device__ __forceinline__ void cst2(float* p, float a, float b){
  u64 v = ((u64)__float_as_uint(b) << 32) | (u64)__float_as_uint(a);
  __hip_atomic_store((u64*)p, v, __ATOMIC_RELAXED, __HIP_MEMORY_SCOPE_AGENT);
}

// hierarchical full grid barrier: 32 groups x 8 blocks, monotonic phase counters.
__device__ __forceinline__ void gbar(unsigned* bar, unsigned ph){
  __syncthreads();
  if (threadIdx.x == 0){
    const unsigned g = blockIdx.x & 31u;
    asm volatile("s_waitcnt vmcnt(0)" ::: "memory");
    unsigned old = __hip_atomic_fetch_add(&bar[g*64], 1u, __ATOMIC_RELAXED, __HIP_MEMORY_SCOPE_AGENT);
    if (old == ph*8u - 1u){
      unsigned t = __hip_atomic_fetch_add(&bar[2048], 1u, __ATOMIC_RELAXED, __HIP_MEMORY_SCOPE_AGENT);
      if (t == ph*32u - 1u)
        __hip_atomic_store(&bar[2112], ph, __ATOMIC_RELAXED, __HIP_MEMORY_SCOPE_AGENT);
    }
    if (blockIdx.x < 32){
      while (__hip_atomic_load(&bar[2112], __ATOMIC_RELAXED, __HIP_MEMORY_SCOPE_AGENT) < ph)
        __builtin_amdgcn_s_sleep(2);
      __hip_atomic_store(&bar[2176 + blockIdx.x*64], ph, __ATOMIC_RELAXED, __HIP_MEMORY_SCOPE_AGENT);
    } else {
      while (__hip_atomic_load(&bar[2176 + g*64], __ATOMIC_RELAXED, __HIP_MEMORY_SCOPE_AGENT) < ph)
        __builtin_amdgcn_s_sleep(2);
    }
  }
  __syncthreads();
}

// per-batch barrier: 32 blocks (blk>>5 == b), counter at 6144 + b*64
__device__ __forceinline__ void bbar(unsigned* bar, int b, unsigned phb){
  __syncthreads();
  if (threadIdx.x == 0){
    unsigned* cnt = &bar[6144 + b*64];
    asm volatile("s_waitcnt vmcnt(0)" ::: "memory");
    __hip_atomic_fetch_add(cnt, 1u, __ATOMIC_RELAXED, __HIP_MEMORY_SCOPE_AGENT);
    while (__hip_atomic_load(cnt, __ATOMIC_RELAXED, __HIP_MEMORY_SCOPE_AGENT) < phb*32u)
      __builtin_amdgcn_s_sleep(2);
  }
  __syncthreads();
}

// ---------------- init
__launch_bounds__(256)
__global__ void k_init(const float* __restrict__ x, float* __restrict__ ws){
  int i = blockIdx.x*256 + threadIdx.x;
  int r = i >> 7, m = i & 127;
  int t = r >> 3, b = r & 7;
  ws[WS_XIN + i] = x[b*8192 + m*64 + t];
  if (i < 2048){ ws[WS_HH + i] = 0.f; ws[WS_C + i] = 0.f; }
}

// ---------------- fp32 -> fp16 bulk convert (16M elements: grid 8192)
__launch_bounds__(256)
__global__ void k_wk16(const float* __restrict__ in, __half* __restrict__ out){
  size_t i = ((size_t)blockIdx.x*256 + threadIdx.x)*8;
  float4 a = *(const float4*)(in + i);
  float4 b = *(const float4*)(in + i + 4);
  uint4 v;
  __half2* vp = (__half2*)&v;
  vp[0] = __floats2half2_rn(a.x, a.y);
  vp[1] = __floats2half2_rn(a.z, a.w);
  vp[2] = __floats2half2_rn(b.x, b.y);
  vp[3] = __floats2half2_rn(b.z, b.w);
  *(uint4*)(out + i) = v;
}

// ---------------- generic fp32 GEMM (act: 0 none, 1 relu, 2 sigmoid)
__launch_bounds__(256)
__global__ void k_gemm_nt(const float* __restrict__ W, const float* __restrict__ X,
                          const float* __restrict__ b1, const float* __restrict__ b2,
                          float* __restrict__ out, int M, int K, int act){
  __shared__ float Wt[32*132];
  __shared__ float Xt[32*132];
  const int tid = threadIdx.x;
  const int tx = tid & 15, ty = tid >> 4;
  const int m0 = blockIdx.x * 128, n0 = blockIdx.y * 128;
  float acc[8][8];
  #pragma unroll
  for (int i = 0; i < 8; i++)
    #pragma unroll
    for (int j = 0; j < 8; j++) acc[i][j] = 0.f;

  for (int k0 = 0; k0 < K; k0 += 32){
    #pragma unroll
    for (int i = 0; i < 4; i++){
      int f4 = i*256 + tid;
      int row = f4 >> 3;
      int j4 = (f4 & 7) * 4;
      float4 w = *(const float4*)&W[(size_t)(m0+row)*K + k0 + j4];
      Wt[(j4+0)*132 + row] = w.x;
      Wt[(j4+1)*132 + row] = w.y;
      Wt[(j4+2)*132 + row] = w.z;
      Wt[(j4+3)*132 + row] = w.w;
      float4 xv = *(const float4*)&X[(size_t)(n0+row)*K + k0 + j4];
      Xt[(j4+0)*132 + row] = xv.x;
      Xt[(j4+1)*132 + row] = xv.y;
      Xt[(j4+2)*132 + row] = xv.z;
      Xt[(j4+3)*132 + row] = xv.w;
    }
    __syncthreads();
    for (int k = 0; k < 32; k++){
      float4 a0 = *(const float4*)&Wt[k*132 + 4*tx];
      float4 a1 = *(const float4*)&Wt[k*132 + 64 + 4*tx];
      float4 x0 = *(const float4*)&Xt[k*132 + 4*ty];
      float4 x1 = *(const float4*)&Xt[k*132 + 64 + 4*ty];
      float am[8] = {a0.x,a0.y,a0.z,a0.w,a1.x,a1.y,a1.z,a1.w};
      float xn[8] = {x0.x,x0.y,x0.z,x0.w,x1.x,x1.y,x1.z,x1.w};
      #pragma unroll
      for (int mi = 0; mi < 8; mi++)
        #pragma unroll
        for (int ni = 0; ni < 8; ni++)
          acc[mi][ni] += am[mi]*xn[ni];
    }
    __syncthreads();
  }

  float bvv[8];
  #pragma unroll
  for (int mi = 0; mi < 8; mi++){
    int m = m0 + ((mi < 4) ? (4*tx + mi) : (64 + 4*tx + mi - 4));
    float bb = b1[m];
    if (b2) bb += b2[m];
    bvv[mi] = bb;
  }
  #pragma unroll
  for (int ni = 0; ni < 8; ni++){
    int n = n0 + ((ni < 4) ? (4*ty + ni) : (64 + 4*ty + ni - 4));
    float v[8];
    #pragma unroll
    for (int mi = 0; mi < 8; mi++){
      float q = acc[mi][ni] + bvv[mi];
      if (act == 1) q = fmaxf(q, 0.f);
      else if (act == 2) q = 1.0f/(1.0f + expf(-q));
      v[mi] = q;
    }
    *(float4*)&out[(size_t)n*M + m0 + 4*tx]      = make_float4(v[0],v[1],v[2],v[3]);
    *(float4*)&out[(size_t)n*M + m0 + 64 + 4*tx] = make_float4(v[4],v[5],v[6],v[7]);
  }
}

// ---------------- Q GEMM: out[n][m](fp16) = X[n]·Wh[m] + b1[m], M=65536 K=256
// fp16 operands, fp32 accumulate via v_dot2_f32_f16
__launch_bounds__(256)
__global__ void k_gemmq(const __half* __restrict__ Wh, const float* __restrict__ X,
                        const float* __restrict__ b1, __half* __restrict__ out){
  __shared__ __half2 Wt[16*132];
  __shared__ __half2 Xt[16*132];
  const int tid = threadIdx.x;
  const int tx = tid & 15, ty = tid >> 4;
  const int m0 = blockIdx.x * 128, n0 = blockIdx.y * 128;
  float acc[8][8];
  #pragma unroll
  for (int i = 0; i < 8; i++)
    #pragma unroll
    for (int j = 0; j < 8; j++) acc[i][j] = 0.f;

  for (int k0 = 0; k0 < 256; k0 += 32){
    // stage W (fp16): 128 rows x 16 half2; 2 uint4 per thread
    #pragma unroll
    for (int i = 0; i < 2; i++){
      int f = i*256 + tid;
      int row = f >> 2, q = f & 3;
      uint4 wv = *(const uint4*)(Wh + (size_t)(m0+row)*256 + k0 + q*8);
      const __half2* wp = (const __half2*)&wv;
      #pragma unroll
      for (int j = 0; j < 4; j++)
        Wt[(q*4 + j)*132 + row] = wp[j];
    }
    // stage X (fp32 -> half2): 128 rows x 8 float4; 4 per thread
    #pragma unroll
    for (int i = 0; i < 4; i++){
      int f = i*256 + tid;
      int row = f >> 3, q = f & 7;
      float4 xv = *(const float4*)&X[(size_t)(n0+row)*256 + k0 + q*4];
      Xt[(q*2    )*132 + row] = __floats2half2_rn(xv.x, xv.y);
      Xt[(q*2 + 1)*132 + row] = __floats2half2_rn(xv.z, xv.w);
    }
    __syncthreads();
    for (int k2 = 0; k2 < 16; k2++){
      __half2 am[8], xn[8];
      #pragma unroll
      for (int s = 0; s < 4; s++){
        am[s]   = Wt[k2*132 + 4*tx + s];
        am[4+s] = Wt[k2*132 + 64 + 4*tx + s];
        xn[s]   = Xt[k2*132 + 4*ty + s];
        xn[4+s] = Xt[k2*132 + 64 + 4*ty + s];
      }
      #pragma unroll
      for (int mi = 0; mi < 8; mi++)
        #pragma unroll
        for (int ni = 0; ni < 8; ni++)
          acc[mi][ni] = fdot2c(am[mi], xn[ni], acc[mi][ni]);
    }
    __syncthreads();
  }

  float bvv[8];
  #pragma unroll
  for (int mi = 0; mi < 8; mi++){
    int m = m0 + ((mi < 4) ? (4*tx + mi) : (64 + 4*tx + mi - 4));
    bvv[mi] = b1[m];
  }
  #pragma unroll
  for (int ni = 0; ni < 8; ni++){
    int n = n0 + ((ni < 4) ? (4*ty + ni) : (64 + 4*ty + ni - 4));
    float v[8];
    #pragma unroll
    for (int mi = 0; mi < 8; mi++) v[mi] = acc[mi][ni] + bvv[mi];
    uint2 u0, u1;
    __half2* up0 = (__half2*)&u0;
    __half2* up1 = (__half2*)&u1;
    up0[0] = __floats2half2_rn(v[0], v[1]);
    up0[1] = __floats2half2_rn(v[2], v[3]);
    up1[0] = __floats2half2_rn(v[4], v[5]);
    up1[1] = __floats2half2_rn(v[6], v[7]);
    *(uint2*)&out[(size_t)n*65536 + m0 + 4*tx]      = u0;
    *(uint2*)&out[(size_t)n*65536 + m0 + 64 + 4*tx] = u1;
  }
}

// ---------------- feature extractor conv chain
__launch_bounds__(256)
__global__ void k_feconv(const float* __restrict__ gf, const float* __restrict__ c1w,
                         const float* __restrict__ c1b, const float* __restrict__ c2w,
                         const float* __restrict__ c2b, const float* __restrict__ c3w,
                         const float* __restrict__ c3b, float* __restrict__ fs){
  __shared__ float fc[1024];
  __shared__ float p1[16*512];
  __shared__ float p2[32*256];
  __shared__ float w1[48], w2[1536], w3[96], bb1[16], bb2[32];
  const int r = blockIdx.x, tid = threadIdx.x;
  #pragma unroll
  for (int i = 0; i < 4; i++) fc[i*256 + tid] = gf[(size_t)r*1024 + i*256 + tid];
  if (tid < 48) w1[tid] = c1w[tid];
  if (tid < 16) bb1[tid] = c1b[tid];
  for (int i = tid; i < 1536; i += 256) w2[i] = c2w[i];
  if (tid < 32) bb2[tid] = c2b[tid];
  if (tid < 96) w3[tid] = c3w[tid];
  __syncthreads();
  for (int i = 0; i < 32; i++){
    int idx = i*256 + tid;
    int ch = idx >> 9, p = idx & 511;
    float k0 = w1[ch*3], k1 = w1[ch*3+1], k2 = w1[ch*3+2], bias = bb1[ch];
    int q = 2*p;
    float xm1 = (q >= 1) ? fc[q-1] : 0.f;
    float x0 = fc[q];
    float x1 = fc[q+1];
    float x2 = (q+2 < 1024) ? fc[q+2] : 0.f;
    float a0 = bias + k0*xm1 + k1*x0 + k2*x1;
    float a1 = bias + k0*x0 + k1*x1 + k2*x2;
    p1[ch*512 + p] = fmaxf(fmaxf(a0, 0.f), fmaxf(a1, 0.f));
  }
  __syncthreads();
  for (int i = 0; i < 32; i++){
    int idx = i*256 + tid;
    int ch = idx >> 8, p = idx & 255;
    float a0 = bb2[ch], a1 = bb2[ch];
    int q = 2*p;
    #pragma unroll
    for (int ci = 0; ci < 16; ci++){
      const float* wp = &w2[(ch*16+ci)*3];
      const float* ip = &p1[ci*512];
      float xm1 = (q >= 1) ? ip[q-1] : 0.f;
      float x0 = ip[q];
      float x1 = ip[q+1];
      float x2 = (q+2 < 512) ? ip[q+2] : 0.f;
      a0 += wp[0]*xm1 + wp[1]*x0 + wp[2]*x1;
      a1 += wp[0]*x0  + wp[1]*x1 + wp[2]*x2;
    }
    p2[ch*256 + p] = fmaxf(fmaxf(a0, 0.f), fmaxf(a1, 0.f));
  }
  __syncthreads();
  if (tid < 256){
    float a = c3b[0];
    const int l = tid;
    #pragma unroll
    for (int ci = 0; ci < 32; ci++){
      const float* wp = &w3[ci*3];
      const float* ip = &p2[ci*256];
      float xm1 = (l >= 1) ? ip[l-1] : 0.f;
      float x0 = ip[l];
      float x2 = (l+1 < 256) ? ip[l+1] : 0.f;
      a += wp[0]*xm1 + wp[1]*x0 + wp[2]*x2;
    }
    fs[(size_t)r*256 + l] = a;
  }
}

// ---------------- Wv_eff + barrier region init
__launch_bounds__(256)
__global__ void k_wveff(const float* __restrict__ Wv, const float* __restrict__ bvq,
                        const float* __restrict__ Wao, float* __restrict__ wve,
                        float* __restrict__ bve, unsigned* __restrict__ bar){
  __shared__ float wa[256];
  const int g = blockIdx.x, tid = threadIdx.x;
  if (g == 0){
    for (int i = tid; i < 8192; i += 256) bar[i] = 0u;
  }
  wa[tid] = Wao[tid];
  __syncthreads();
  float acc = 0.f;
  for (int d = 0; d < 256; d++)
    acc += Wv[((size_t)(g*256 + d))*256 + tid] * wa[d];
  wve[g*256 + tid] = acc;
  if (tid == 0){
    float s = 0.f;
    for (int d = 0; d < 256; d++) s += bvq[g*256 + d]*wa[d];
    bve[g] = s;
  }
}

// ---------------- persistent recurrent loop (R10 structure; per-batch barrier 3)
__global__ __launch_bounds__(512, 2)
void k_loop(const float* __restrict__ gx, const float* __restrict__ Wh,
            const __half* __restrict__ wkh, const float* __restrict__ bkb,
            const float* __restrict__ wve, const float* __restrict__ bve,
            const __half* __restrict__ Qh, const float* __restrict__ bao,
            const float* __restrict__ Wout, const float* __restrict__ bout,
            float* __restrict__ c, float* __restrict__ og, float* __restrict__ vw,
            float* __restrict__ Kt, float* __restrict__ stats, float* __restrict__ hH,
            float* __restrict__ y, unsigned* __restrict__ bar){
  __shared__ float S[25088];
  const int blk = blockIdx.x, tid = threadIdx.x;
  unsigned ph = 0, phb = 0;
  const float bao0 = bao[0];

  const int p1_b = blk >> 5, p1_s = blk & 31;
  const int gid  = blk;
  const int p3_b = blk >> 5, p3_ht = (blk >> 2) & 7, p3_gt = blk & 3;
  const int p3_h0 = p3_ht*32, p3_g0 = p3_gt*64;

  // hoist Wh fragment for P1
  float4 whr[4];
  int p1_row;
  {
    const int j = tid >> 4, part = tid & 15;
    const int rr = p1_s*32 + j, o = rr >> 2, gate = rr & 3;
    p1_row = gate*256 + o;
    const float4* wr = (const float4*)(Wh + (size_t)p1_row*256);
    #pragma unroll
    for (int u = 0; u < 4; u++) whr[u] = wr[u*16 + part];
  }

  for (int t = 0; t < 64; t++){
    // ---------- P1 ----------
    if (t > 0){
      if (tid < 256){
        const float* sp = stats + ((size_t)p1_b*256 + tid)*16;
        float2 a0 = cld2(sp+0);  float2 b0 = cld2(sp+2);
        float2 a1 = cld2(sp+4);  float2 b1 = cld2(sp+6);
        float2 a2 = cld2(sp+8);  float2 b2 = cld2(sp+10);
        float2 a3 = cld2(sp+12); float2 b3 = cld2(sp+14);
        float m = fmaxf(fmaxf(a0.x, a1.x), fmaxf(a2.x, a3.x));
        float e0 = expf(a0.x - m), e1 = expf(a1.x - m), e2 = expf(a2.x - m), e3 = expf(a3.x - m);
        float den = a0.y*e0 + a1.y*e1 + a2.y*e2 + a3.y*e3;
        float num = b0.x*e0 + b1.x*e1 + b2.x*e2 + b3.x*e3;
        float hv = num/den + bao0;
        S[tid] = hv;
        if (p1_s == 0) cst(&hH[(size_t)t*2048 + p1_b*256 + tid], hv);
      }
    } else {
      if (tid < 256) S[tid] = 0.f;
    }
    __syncthreads();
    {
      const int j = tid >> 4, part = tid & 15;
      const float4* h4 = (const float4*)S;
      float a0 = 0.f;
      #pragma unroll
      for (int u = 0; u < 4; u++)
        a0 += dot4(whr[u], h4[u*16 + part]);
      a0 += __shfl_xor(a0, 1);
      a0 += __shfl_xor(a0, 2);
      a0 += __shfl_xor(a0, 4);
      a0 += __shfl_xor(a0, 8);
      if (part == 0) S[256 + j] = a0 + gx[(size_t)(t*8 + p1_b)*1024 + p1_row];
    }
    __syncthreads();
    if (tid < 8){
      const int o_ = p1_s*8 + tid, ci = p1_b*256 + o_;
      float ig = sigmf(S[256 + tid*4 + 0]);
      float fg = sigmf(S[256 + tid*4 + 1]);
      float gg = tanhf(S[256 + tid*4 + 2]);
      float ov = sigmf(S[256 + tid*4 + 3]);
      float cv = cld(&c[ci]);
      cst(&c[ci], fg*cv + ig*gg);
      cst(&og[ci], ov);
    }
    gbar(bar, ++ph);

    // ---------- P2: K[:, g=gid, :] = Wk16 . c ; vw[:, gid] ----------
    {
      int bb0 = tid >> 6, j40 = tid & 63;
      float* dst = &S[bb0*260 + j40*4];
      const float* src = &c[bb0*256 + j40*4];
      float2 v0 = cld2(src);
      float2 v1 = cld2(src+2);
      dst[0] = v0.x; dst[1] = v0.y; dst[2] = v1.x; dst[3] = v1.y;
    }
    __syncthreads();
    if (tid < 64){
      const int bb = tid >> 3, part = tid & 7;
      const float4* wv4 = (const float4*)(wve + gid*256);
      float sacc = 0.f;
      #pragma unroll
      for (int u = 0; u < 8; u++){
        float4 w = wv4[part*8 + u];
        const float* op = &og[bb*256 + (part*8 + u)*4];
        float2 o0 = cld2(op);
        float2 o1 = cld2(op+2);
        sacc += w.x*o0.x + w.y*o0.y + w.z*o1.x + w.w*o1.y;
      }
      sacc += __shfl_xor(sacc, 1);
      sacc += __shfl_xor(sacc, 2);
      sacc += __shfl_xor(sacc, 4);
      if (part == 0) cst(&vw[bb*256 + gid], sacc + bve[gid]);
    }
    {
      const float4* cl4 = (const float4*)S;
      #pragma unroll 2
      for (int p = 0; p < 8; p++){
        const int d = p*32 + (tid >> 4), part = tid & 15;
        const __half* wr = wkh + ((size_t)gid*256 + d)*256;
        float4 w0 = h4_to_f4(*(const uint2*)(wr + part*4));
        float4 w1 = h4_to_f4(*(const uint2*)(wr + 64 + part*4));
        float4 w2 = h4_to_f4(*(const uint2*)(wr + 128 + part*4));
        float4 w3 = h4_to_f4(*(const uint2*)(wr + 192 + part*4));
        float acc[8];
        #pragma unroll
        for (int bb = 0; bb < 8; bb++){
          acc[bb] = dot4(w0, cl4[bb*65 + part]) + dot4(w1, cl4[bb*65 + 16 + part])
                  + dot4(w2, cl4[bb*65 + 32 + part]) + dot4(w3, cl4[bb*65 + 48 + part]);
        }
        #pragma unroll
        for (int bb = 0; bb < 8; bb++){
          acc[bb] += __shfl_xor(acc[bb], 1);
          acc[bb] += __shfl_xor(acc[bb], 2);
          acc[bb] += __shfl_xor(acc[bb], 4);
          acc[bb] += __shfl_xor(acc[bb], 8);
        }
        const float bkv = bkb[gid*256 + d];
        if (part < 8)
          cst(&Kt[(size_t)part*65536 + gid*256 + d], acc[part] + bkv);
      }
    }
    gbar(bar, ++ph);

    // ---------- P3: partial attention stats for (b, 32h, 64g) ----------
    {
      const __half* Qb = Qh + ((size_t)(t*8 + p3_b))*65536 + (size_t)p3_h0*256;
      #pragma unroll
      for (int i = 0; i < 2; i++){
        int f8 = i*512 + tid;
        int hh = f8 >> 5, j8 = f8 & 31;
        uint4 v = *(const uint4*)(Qb + hh*256 + j8*8);
        float4 a, b;
        h8_to_f8(v, a, b);
        float* dst = &S[hh*260 + j8*8];
        *(float4*)dst = a;
        *(float4*)(dst+4) = b;
      }
      const float* Kb = Kt + (size_t)p3_b*65536 + (size_t)p3_g0*256;
      float* Kl = S + 8320;
      #pragma unroll
      for (int i = 0; i < 8; i++){
        int f4 = i*512 + tid;
        int gg = f4 >> 6, j4 = (f4 & 63)*4;
        float* dst = &Kl[gg*260 + j4];
        const float* src = &Kb[gg*256 + j4];
        float2 v0 = cld2(src);
        float2 v1 = cld2(src+2);
        dst[0] = v0.x; dst[1] = v0.y; dst[2] = v1.x; dst[3] = v1.y;
      }
      if (tid < 64) S[24960 + tid] = cld(&vw[p3_b*256 + p3_g0 + tid]);
      __syncthreads();
      const int kh = tid >> 7, r = tid & 127, ty = r >> 4, txl = r & 15;
      float acc[4][4];
      #pragma unroll
      for (int a = 0; a < 4; a++)
        #pragma unroll
        for (int i = 0; i < 4; i++) acc[a][i] = 0.f;
      const float4* Ql4 = (const float4*)S;
      const float4* Kl4 = (const float4*)(S + 8320);
      for (int k4 = 0; k4 < 16; k4++){
        const int kk = kh*16 + k4;
        float4 qv[4], kv[4];
        #pragma unroll
        for (int a = 0; a < 4; a++) qv[a] = Ql4[(ty + 8*a)*65 + kk];
        #pragma unroll
        for (int i = 0; i < 4; i++) kv[i] = Kl4[(txl + 16*i)*65 + kk];
        #pragma unroll
        for (int a = 0; a < 4; a++)
          #pragma unroll
          for (int i = 0; i < 4; i++)
            acc[a][i] += dot4(qv[a], kv[i]);
      }
      __syncthreads();
      float* Pl = S;
      if (kh > 0){
        #pragma unroll
        for (int a = 0; a < 4; a++)
          #pragma unroll
          for (int i = 0; i < 4; i++)
            Pl[(kh-1)*2048 + r*16 + a*4 + i] = acc[a][i];
      }
      __syncthreads();
      if (kh == 0){
        #pragma unroll
        for (int p = 0; p < 3; p++)
          #pragma unroll
          for (int a = 0; a < 4; a++)
            #pragma unroll
            for (int i = 0; i < 4; i++)
              acc[a][i] += Pl[p*2048 + r*16 + a*4 + i];
        #pragma unroll
        for (int a = 0; a < 4; a++)
          #pragma unroll
          for (int i = 0; i < 4; i++)
            acc[a][i] *= 0.0625f;
        #pragma unroll
        for (int a = 0; a < 4; a++){
          float mx = fmaxf(fmaxf(acc[a][0], acc[a][1]), fmaxf(acc[a][2], acc[a][3]));
          mx = fmaxf(mx, __shfl_xor(mx, 1));
          mx = fmaxf(mx, __shfl_xor(mx, 2));
          mx = fmaxf(mx, __shfl_xor(mx, 4));
          mx = fmaxf(mx, __shfl_xor(mx, 8));
          float den = 0.f, num = 0.f;
          #pragma unroll
          for (int i = 0; i < 4; i++){
            float pv = expf(acc[a][i] - mx);
            den += pv;
            num += pv * S[24960 + txl + 16*i];
          }
          den += __shfl_xor(den, 1); num += __shfl_xor(num, 1);
          den += __shfl_xor(den, 2); num += __shfl_xor(num, 2);
          den += __shfl_xor(den, 4); num += __shfl_xor(num, 4);
          den += __shfl_xor(den, 8); num += __shfl_xor(num, 8);
          if (txl == 0){
            const int h = p3_h0 + ty + 8*a;
            float* sp = &stats[(((size_t)p3_b*256 + h)*4 + p3_gt)*4];
            cst2(sp, mx, den);
            cst(sp+2, num);
          }
        }
      }
    }
    bbar(bar, p3_b, ++phb);   // per-batch: stats(b) -> P1(b) of next step
  }

  // ---------- tail ----------
  if (p1_s == 0 && tid < 256){
    const float* sp = stats + ((size_t)p1_b*256 + tid)*16;
    float2 a0 = cld2(sp+0);  float2 b0 = cld2(sp+2);
    float2 a1 = cld2(sp+4);  float2 b1 = cld2(sp+6);
    float2 a2 = cld2(sp+8);  float2 b2 = cld2(sp+10);
    float2 a3 = cld2(sp+12); float2 b3 = cld2(sp+14);
    float m = fmaxf(fmaxf(a0.x, a1.x), fmaxf(a2.x, a3.x));
    float e0 = expf(a0.x - m), e1 = expf(a1.x - m), e2 = expf(a2.x - m), e3 = expf(a3.x - m);
    float den = a0.y*e0 + a1.y*e1 + a2.y*e2 + a3.y*e3;
    float num = b0.x*e0 + b1.x*e1 + b2.x*e2 + b3.x*e3;
    cst(&hH[(size_t)64*2048 + p1_b*256 + tid], num/den + bao0);
  }
  gbar(bar, ++ph);
  if (blk < 64 && tid < 80){
    const int t2 = blk;
    const int bb2 = tid/10, cc = tid - bb2*10;
    const float* hr = &hH[(size_t)(t2+1)*2048 + bb2*256];
    const float* wr2 = &Wout[cc*256];
    float acc = 0.f;
    for (int u = 0; u < 128; u++){
      float2 h2 = cld2(hr + u*2);
      acc += h2.x*wr2[u*2] + h2.y*wr2[u*2+1];
    }
    y[bb2*640 + cc*64 + t2] = acc + bout[cc];
  }
}

extern "C" void kernel_launch(void* const* d_in, const int* in_sizes, int n_in,
                              void* d_out, int out_size, void* d_ws, size_t ws_size,
                              hipStream_t stream){
  (void)in_sizes; (void)n_in; (void)out_size; (void)ws_size;
  const float* x      = (const float*)d_in[0];
  const float* w_init = (const float*)d_in[1];
  const float* b_init = (const float*)d_in[2];
  const float* c1w    = (const float*)d_in[3];
  const float* c1b    = (const float*)d_in[4];
  const float* c2w    = (const float*)d_in[5];
  const float* c2b    = (const float*)d_in[6];
  const float* c3w    = (const float*)d_in[7];
  const float* c3b    = (const float*)d_in[8];
  const float* Wx     = (const float*)d_in[9];
  const float* bx     = (const float*)d_in[10];
  const float* Wh     = (const float*)d_in[11];
  const float* bh     = (const float*)d_in[12];
  const float* Wxo    = (const float*)d_in[13];
  const float* bxo    = (const float*)d_in[14];
  const float* Wq     = (const float*)d_in[15];
  const float* bq     = (const float*)d_in[16];
  const float* Wk     = (const float*)d_in[17];
  const float* bk_    = (const float*)d_in[18];
  const float* Wv     = (const float*)d_in[19];
  const float* bv     = (const float*)d_in[20];
  const float* Wao    = (const float*)d_in[21];
  const float* bao    = (const float*)d_in[22];
  const float* Wout   = (const float*)d_in[23];
  const float* bout   = (const float*)d_in[24];
  float* y  = (float*)d_out;
  float* ws = (float*)d_ws;

  float* xin   = ws + WS_XIN;
  float* gf    = ws + WS_GF;
  float* stats = ws + WS_STATS;
  unsigned* bar = (unsigned*)(ws + WS_BARS);
  float* fs    = ws + WS_FS;
  float* xo    = ws + WS_XO;
  float* gxp   = ws + WS_GX;
  __half* Qh   = (__half*)(ws + WS_Q);
  __half* wkh  = (__half*)(ws + WS_WKH);
  __half* wqh  = (__half*)(ws + WS_WQH);
  float* wve   = ws + WS_WVE;
  float* bve   = ws + WS_BVE;
  float* Ktp   = ws + WS_KT;
  float* hH    = ws + WS_HH;
  float* cp    = ws + WS_C;
  float* ogp   = ws + WS_OG;
  float* vwp   = ws + WS_VW;

  k_init<<<256, 256, 0, stream>>>(x, ws);
  k_wk16<<<8192, 256, 0, stream>>>(Wk, wkh);
  k_wk16<<<8192, 256, 0, stream>>>(Wq, wqh);
  k_gemm_nt<<<dim3(8, 4), 256, 0, stream>>>(w_init, xin, b_init, nullptr, gf, 1024, 128, 1);
  k_feconv<<<512, 256, 0, stream>>>(gf, c1w, c1b, c2w, c2b, c3w, c3b, fs);
  k_gemm_nt<<<dim3(2, 4), 256, 0, stream>>>(Wxo, fs, bxo, nullptr, xo, 256, 256, 2);
  k_gemm_nt<<<dim3(8, 4), 256, 0, stream>>>(Wx, fs, bx, bh, gxp, 1024, 256, 0);
  k_wveff<<<256, 256, 0, stream>>>(Wv, bv, Wao, wve, bve, bar);
  k_gemmq<<<dim3(512, 4), 256, 0, stream>>>(wqh, xo, bq, Qh);
  k_loop<<<NBLK, 512, 0, stream>>>(gxp, Wh, wkh, bk_, wve, bve, Qh, bao, Wout, bout,
                                   cp, ogp, vwp, Ktp, stats, hH, y, bar);
}

// Round 15
// 2475.503 us; speedup vs baseline: 1.8124x; 1.0007x over previous
//
#include <hip/hip_runtime.h>
#include <hip/hip_fp16.h>
#include <math.h>

// Workspace layout (float offsets)
#define WS_XIN   0L
#define WS_GF    65536L
#define WS_STATS 65536L      // [8][256][4][4] softmax partials
#define WS_BARS  98304L      // barrier region: 8192 unsigned words
#define WS_FS    589824L
#define WS_XO    720896L
#define WS_GX    851968L
#define WS_Q     1376256L    // fp16 [512][65536]  -> ends 18153472
#define WS_WKH   18153472L   // fp16 [65536][256]  -> ends 26542080
#define WS_WQH   26542080L   // fp16 [65536][256]  -> ends 34930688
#define WS_WVE   34930688L
#define WS_BVE   34996224L
#define WS_KT    34996480L   // fp32 Kt[b][g][d]
#define WS_HH    35520768L   // [65][2048]
#define WS_C     35653888L
#define WS_OG    35655936L
#define WS_VW    35657984L

#define NBLK 256

typedef unsigned long long u64;
typedef _Float16 h2v __attribute__((ext_vector_type(2)));

__device__ __forceinline__ float sigmf(float x){ return 1.0f/(1.0f + expf(-x)); }
__device__ __forceinline__ float dot4(float4 a, float4 b){
  return a.x*b.x + a.y*b.y + a.z*b.z + a.w*b.w;
}
__device__ __forceinline__ void h8_to_f8(uint4 v, float4& a, float4& b){
  const __half2* hp = (const __half2*)&v;
  float2 f0 = __half22float2(hp[0]);
  float2 f1 = __half22float2(hp[1]);
  float2 f2 = __half22float2(hp[2]);
  float2 f3 = __half22float2(hp[3]);
  a = make_float4(f0.x, f0.y, f1.x, f1.y);
  b = make_float4(f2.x, f2.y, f3.x, f3.y);
}
__device__ __forceinline__ float4 h4_to_f4(uint2 v){
  const __half2* hp = (const __half2*)&v;
  float2 f0 = __half22float2(hp[0]);
  float2 f1 = __half22float2(hp[1]);
  return make_float4(f0.x, f0.y, f1.x, f1.y);
}
__device__ __forceinline__ float fdot2c(__half2 a, __half2 b, float c){
#if __has_builtin(__builtin_amdgcn_fdot2)
  h2v av = *(h2v*)&a;
  h2v bv = *(h2v*)&b;
  return __builtin_amdgcn_fdot2(av, bv, c, false);
#else
  float2 af = __half22float2(a);
  float2 bf = __half22float2(b);
  return fmaf(af.y, bf.y, fmaf(af.x, bf.x, c));
#endif
}

// coherent (device-point) accesses for cross-block mutable data — AGENT scope
__device__ __forceinline__ float cld(const float* p){
  return __hip_atomic_load((float*)p, __ATOMIC_RELAXED, __HIP_MEMORY_SCOPE_AGENT);
}
__device__ __forceinline__ void cst(float* p, float v){
  __hip_atomic_store(p, v, __ATOMIC_RELAXED, __HIP_MEMORY_SCOPE_AGENT);
}
__device__ __forceinline__ float2 cld2(const float* p){
  u64 v = __hip_atomic_load((const u64*)p, __ATOMIC_RELAXED, __HIP_MEMORY_SCOPE_AGENT);
  float2 r;
  r.x = __uint_as_float((unsigned)(v & 0xffffffffu));
  r.y = __uint_as_float((unsigned)(v >> 32));
  return r;
}
__device__ __forceinline__ void cst2(float* p, float a, float b){
  u64 v = ((u64)__float_as_uint(b) << 32) | (u64)__float_as_uint(a);
  __hip_atomic_store((u64*)p, v, __ATOMIC_RELAXED, __HIP_MEMORY_SCOPE_AGENT);
}

// hierarchical full grid barrier: 32 groups x 8 blocks, monotonic phase counters.
__device__ __forceinline__ void gbar(unsigned* bar, unsigned ph){
  __syncthreads();
  if (threadIdx.x == 0){
    const unsigned g = blockIdx.x & 31u;
    asm volatile("s_waitcnt vmcnt(0)" ::: "memory");
    unsigned old = __hip_atomic_fetch_add(&bar[g*64], 1u, __ATOMIC_RELAXED, __HIP_MEMORY_SCOPE_AGENT);
    if (old == ph*8u - 1u){
      unsigned t = __hip_atomic_fetch_add(&bar[2048], 1u, __ATOMIC_RELAXED, __HIP_MEMORY_SCOPE_AGENT);
      if (t == ph*32u - 1u)
        __hip_atomic_store(&bar[2112], ph, __ATOMIC_RELAXED, __HIP_MEMORY_SCOPE_AGENT);
    }
    if (blockIdx.x < 32){
      while (__hip_atomic_load(&bar[2112], __ATOMIC_RELAXED, __HIP_MEMORY_SCOPE_AGENT) < ph)
        __builtin_amdgcn_s_sleep(2);
      __hip_atomic_store(&bar[2176 + blockIdx.x*64], ph, __ATOMIC_RELAXED, __HIP_MEMORY_SCOPE_AGENT);
    } else {
      while (__hip_atomic_load(&bar[2176 + g*64], __ATOMIC_RELAXED, __HIP_MEMORY_SCOPE_AGENT) < ph)
        __builtin_amdgcn_s_sleep(2);
    }
  }
  __syncthreads();
}

// per-batch barrier: 32 blocks (blk>>5 == b), counter at 6144 + b*64
__device__ __forceinline__ void bbar(unsigned* bar, int b, unsigned phb){
  __syncthreads();
  if (threadIdx.x == 0){
    unsigned* cnt = &bar[6144 + b*64];
    asm volatile("s_waitcnt vmcnt(0)" ::: "memory");
    __hip_atomic_fetch_add(cnt, 1u, __ATOMIC_RELAXED, __HIP_MEMORY_SCOPE_AGENT);
    while (__hip_atomic_load(cnt, __ATOMIC_RELAXED, __HIP_MEMORY_SCOPE_AGENT) < phb*32u)
      __builtin_amdgcn_s_sleep(2);
  }
  __syncthreads();
}

// ---------------- init
__launch_bounds__(256)
__global__ void k_init(const float* __restrict__ x, float* __restrict__ ws){
  int i = blockIdx.x*256 + threadIdx.x;
  int r = i >> 7, m = i & 127;
  int t = r >> 3, b = r & 7;
  ws[WS_XIN + i] = x[b*8192 + m*64 + t];
  if (i < 2048){ ws[WS_HH + i] = 0.f; ws[WS_C + i] = 0.f; }
}

// ---------------- fp32 -> fp16 bulk convert (16M elements: grid 8192)
__launch_bounds__(256)
__global__ void k_wk16(const float* __restrict__ in, __half* __restrict__ out){
  size_t i = ((size_t)blockIdx.x*256 + threadIdx.x)*8;
  float4 a = *(const float4*)(in + i);
  float4 b = *(const float4*)(in + i + 4);
  uint4 v;
  __half2* vp = (__half2*)&v;
  vp[0] = __floats2half2_rn(a.x, a.y);
  vp[1] = __floats2half2_rn(a.z, a.w);
  vp[2] = __floats2half2_rn(b.x, b.y);
  vp[3] = __floats2half2_rn(b.z, b.w);
  *(uint4*)(out + i) = v;
}

// ---------------- generic fp32 GEMM (act: 0 none, 1 relu, 2 sigmoid)
__launch_bounds__(256)
__global__ void k_gemm_nt(const float* __restrict__ W, const float* __restrict__ X,
                          const float* __restrict__ b1, const float* __restrict__ b2,
                          float* __restrict__ out, int M, int K, int act){
  __shared__ float Wt[32*132];
  __shared__ float Xt[32*132];
  const int tid = threadIdx.x;
  const int tx = tid & 15, ty = tid >> 4;
  const int m0 = blockIdx.x * 128, n0 = blockIdx.y * 128;
  float acc[8][8];
  #pragma unroll
  for (int i = 0; i < 8; i++)
    #pragma unroll
    for (int j = 0; j < 8; j++) acc[i][j] = 0.f;

  for (int k0 = 0; k0 < K; k0 += 32){
    #pragma unroll
    for (int i = 0; i < 4; i++){
      int f4 = i*256 + tid;
      int row = f4 >> 3;
      int j4 = (f4 & 7) * 4;
      float4 w = *(const float4*)&W[(size_t)(m0+row)*K + k0 + j4];
      Wt[(j4+0)*132 + row] = w.x;
      Wt[(j4+1)*132 + row] = w.y;
      Wt[(j4+2)*132 + row] = w.z;
      Wt[(j4+3)*132 + row] = w.w;
      float4 xv = *(const float4*)&X[(size_t)(n0+row)*K + k0 + j4];
      Xt[(j4+0)*132 + row] = xv.x;
      Xt[(j4+1)*132 + row] = xv.y;
      Xt[(j4+2)*132 + row] = xv.z;
      Xt[(j4+3)*132 + row] = xv.w;
    }
    __syncthreads();
    for (int k = 0; k < 32; k++){
      float4 a0 = *(const float4*)&Wt[k*132 + 4*tx];
      float4 a1 = *(const float4*)&Wt[k*132 + 64 + 4*tx];
      float4 x0 = *(const float4*)&Xt[k*132 + 4*ty];
      float4 x1 = *(const float4*)&Xt[k*132 + 64 + 4*ty];
      float am[8] = {a0.x,a0.y,a0.z,a0.w,a1.x,a1.y,a1.z,a1.w};
      float xn[8] = {x0.x,x0.y,x0.z,x0.w,x1.x,x1.y,x1.z,x1.w};
      #pragma unroll
      for (int mi = 0; mi < 8; mi++)
        #pragma unroll
        for (int ni = 0; ni < 8; ni++)
          acc[mi][ni] += am[mi]*xn[ni];
    }
    __syncthreads();
  }

  float bvv[8];
  #pragma unroll
  for (int mi = 0; mi < 8; mi++){
    int m = m0 + ((mi < 4) ? (4*tx + mi) : (64 + 4*tx + mi - 4));
    float bb = b1[m];
    if (b2) bb += b2[m];
    bvv[mi] = bb;
  }
  #pragma unroll
  for (int ni = 0; ni < 8; ni++){
    int n = n0 + ((ni < 4) ? (4*ty + ni) : (64 + 4*ty + ni - 4));
    float v[8];
    #pragma unroll
    for (int mi = 0; mi < 8; mi++){
      float q = acc[mi][ni] + bvv[mi];
      if (act == 1) q = fmaxf(q, 0.f);
      else if (act == 2) q = 1.0f/(1.0f + expf(-q));
      v[mi] = q;
    }
    *(float4*)&out[(size_t)n*M + m0 + 4*tx]      = make_float4(v[0],v[1],v[2],v[3]);
    *(float4*)&out[(size_t)n*M + m0 + 64 + 4*tx] = make_float4(v[4],v[5],v[6],v[7]);
  }
}

// ---------------- Q GEMM: out[n][m](fp16) = X[n]·Wh[m] + b1[m], M=65536 K=256
__launch_bounds__(256)
__global__ void k_gemmq(const __half* __restrict__ Wh, const float* __restrict__ X,
                        const float* __restrict__ b1, __half* __restrict__ out){
  __shared__ __half2 Wt[16*132];
  __shared__ __half2 Xt[16*132];
  const int tid = threadIdx.x;
  const int tx = tid & 15, ty = tid >> 4;
  const int m0 = blockIdx.x * 128, n0 = blockIdx.y * 128;
  float acc[8][8];
  #pragma unroll
  for (int i = 0; i < 8; i++)
    #pragma unroll
    for (int j = 0; j < 8; j++) acc[i][j] = 0.f;

  for (int k0 = 0; k0 < 256; k0 += 32){
    #pragma unroll
    for (int i = 0; i < 2; i++){
      int f = i*256 + tid;
      int row = f >> 2, q = f & 3;
      uint4 wv = *(const uint4*)(Wh + (size_t)(m0+row)*256 + k0 + q*8);
      const __half2* wp = (const __half2*)&wv;
      #pragma unroll
      for (int j = 0; j < 4; j++)
        Wt[(q*4 + j)*132 + row] = wp[j];
    }
    #pragma unroll
    for (int i = 0; i < 4; i++){
      int f = i*256 + tid;
      int row = f >> 3, q = f & 7;
      float4 xv = *(const float4*)&X[(size_t)(n0+row)*256 + k0 + q*4];
      Xt[(q*2    )*132 + row] = __floats2half2_rn(xv.x, xv.y);
      Xt[(q*2 + 1)*132 + row] = __floats2half2_rn(xv.z, xv.w);
    }
    __syncthreads();
    for (int k2 = 0; k2 < 16; k2++){
      __half2 am[8], xn[8];
      #pragma unroll
      for (int s = 0; s < 4; s++){
        am[s]   = Wt[k2*132 + 4*tx + s];
        am[4+s] = Wt[k2*132 + 64 + 4*tx + s];
        xn[s]   = Xt[k2*132 + 4*ty + s];
        xn[4+s] = Xt[k2*132 + 64 + 4*ty + s];
      }
      #pragma unroll
      for (int mi = 0; mi < 8; mi++)
        #pragma unroll
        for (int ni = 0; ni < 8; ni++)
          acc[mi][ni] = fdot2c(am[mi], xn[ni], acc[mi][ni]);
    }
    __syncthreads();
  }

  float bvv[8];
  #pragma unroll
  for (int mi = 0; mi < 8; mi++){
    int m = m0 + ((mi < 4) ? (4*tx + mi) : (64 + 4*tx + mi - 4));
    bvv[mi] = b1[m];
  }
  #pragma unroll
  for (int ni = 0; ni < 8; ni++){
    int n = n0 + ((ni < 4) ? (4*ty + ni) : (64 + 4*ty + ni - 4));
    float v[8];
    #pragma unroll
    for (int mi = 0; mi < 8; mi++) v[mi] = acc[mi][ni] + bvv[mi];
    uint2 u0, u1;
    __half2* up0 = (__half2*)&u0;
    __half2* up1 = (__half2*)&u1;
    up0[0] = __floats2half2_rn(v[0], v[1]);
    up0[1] = __floats2half2_rn(v[2], v[3]);
    up1[0] = __floats2half2_rn(v[4], v[5]);
    up1[1] = __floats2half2_rn(v[6], v[7]);
    *(uint2*)&out[(size_t)n*65536 + m0 + 4*tx]      = u0;
    *(uint2*)&out[(size_t)n*65536 + m0 + 64 + 4*tx] = u1;
  }
}

// ---------------- feature extractor conv chain
__launch_bounds__(256)
__global__ void k_feconv(const float* __restrict__ gf, const float* __restrict__ c1w,
                         const float* __restrict__ c1b, const float* __restrict__ c2w,
                         const float* __restrict__ c2b, const float* __restrict__ c3w,
                         const float* __restrict__ c3b, float* __restrict__ fs){
  __shared__ float fc[1024];
  __shared__ float p1[16*512];
  __shared__ float p2[32*256];
  __shared__ float w1[48], w2[1536], w3[96], bb1[16], bb2[32];
  const int r = blockIdx.x, tid = threadIdx.x;
  #pragma unroll
  for (int i = 0; i < 4; i++) fc[i*256 + tid] = gf[(size_t)r*1024 + i*256 + tid];
  if (tid < 48) w1[tid] = c1w[tid];
  if (tid < 16) bb1[tid] = c1b[tid];
  for (int i = tid; i < 1536; i += 256) w2[i] = c2w[i];
  if (tid < 32) bb2[tid] = c2b[tid];
  if (tid < 96) w3[tid] = c3w[tid];
  __syncthreads();
  for (int i = 0; i < 32; i++){
    int idx = i*256 + tid;
    int ch = idx >> 9, p = idx & 511;
    float k0 = w1[ch*3], k1 = w1[ch*3+1], k2 = w1[ch*3+2], bias = bb1[ch];
    int q = 2*p;
    float xm1 = (q >= 1) ? fc[q-1] : 0.f;
    float x0 = fc[q];
    float x1 = fc[q+1];
    float x2 = (q+2 < 1024) ? fc[q+2] : 0.f;
    float a0 = bias + k0*xm1 + k1*x0 + k2*x1;
    float a1 = bias + k0*x0 + k1*x1 + k2*x2;
    p1[ch*512 + p] = fmaxf(fmaxf(a0, 0.f), fmaxf(a1, 0.f));
  }
  __syncthreads();
  for (int i = 0; i < 32; i++){
    int idx = i*256 + tid;
    int ch = idx >> 8, p = idx & 255;
    float a0 = bb2[ch], a1 = bb2[ch];
    int q = 2*p;
    #pragma unroll
    for (int ci = 0; ci < 16; ci++){
      const float* wp = &w2[(ch*16+ci)*3];
      const float* ip = &p1[ci*512];
      float xm1 = (q >= 1) ? ip[q-1] : 0.f;
      float x0 = ip[q];
      float x1 = ip[q+1];
      float x2 = (q+2 < 512) ? ip[q+2] : 0.f;
      a0 += wp[0]*xm1 + wp[1]*x0 + wp[2]*x1;
      a1 += wp[0]*x0  + wp[1]*x1 + wp[2]*x2;
    }
    p2[ch*256 + p] = fmaxf(fmaxf(a0, 0.f), fmaxf(a1, 0.f));
  }
  __syncthreads();
  if (tid < 256){
    float a = c3b[0];
    const int l = tid;
    #pragma unroll
    for (int ci = 0; ci < 32; ci++){
      const float* wp = &w3[ci*3];
      const float* ip = &p2[ci*256];
      float xm1 = (l >= 1) ? ip[l-1] : 0.f;
      float x0 = ip[l];
      float x2 = (l+1 < 256) ? ip[l+1] : 0.f;
      a += wp[0]*xm1 + wp[1]*x0 + wp[2]*x2;
    }
    fs[(size_t)r*256 + l] = a;
  }
}

// ---------------- Wv_eff + barrier region init
__launch_bounds__(256)
__global__ void k_wveff(const float* __restrict__ Wv, const float* __restrict__ bvq,
                        const float* __restrict__ Wao, float* __restrict__ wve,
                        float* __restrict__ bve, unsigned* __restrict__ bar){
  __shared__ float wa[256];
  const int g = blockIdx.x, tid = threadIdx.x;
  if (g == 0){
    for (int i = tid; i < 8192; i += 256) bar[i] = 0u;
  }
  wa[tid] = Wao[tid];
  __syncthreads();
  float acc = 0.f;
  for (int d = 0; d < 256; d++)
    acc += Wv[((size_t)(g*256 + d))*256 + tid] * wa[d];
  wve[g*256 + tid] = acc;
  if (tid == 0){
    float s = 0.f;
    for (int d = 0; d < 256; d++) s += bvq[g*256 + d]*wa[d];
    bve[g] = s;
  }
}

// ---------------- persistent recurrent loop
__global__ __launch_bounds__(512, 2)
void k_loop(const float* __restrict__ gx, const float* __restrict__ Wh,
            const __half* __restrict__ wkh, const float* __restrict__ bkb,
            const float* __restrict__ wve, const float* __restrict__ bve,
            const __half* __restrict__ Qh, const float* __restrict__ bao,
            const float* __restrict__ Wout, const float* __restrict__ bout,
            float* __restrict__ c, float* __restrict__ og, float* __restrict__ vw,
            float* __restrict__ Kt, float* __restrict__ stats, float* __restrict__ hH,
            float* __restrict__ y, unsigned* __restrict__ bar){
  __shared__ float S[25088];
  const int blk = blockIdx.x, tid = threadIdx.x;
  unsigned ph = 0, phb = 0;
  const float bao0 = bao[0];

  const int p1_b = blk >> 5, p1_s = blk & 31;
  const int gid  = blk;
  const int p3_b = blk >> 5, p3_ht = (blk >> 2) & 7, p3_gt = blk & 3;
  const int p3_h0 = p3_ht*32, p3_g0 = p3_gt*64;

  // hoist Wh fragment for P1
  float4 whr[4];
  int p1_row;
  {
    const int j = tid >> 4, part = tid & 15;
    const int rr = p1_s*32 + j, o = rr >> 2, gate = rr & 3;
    p1_row = gate*256 + o;
    const float4* wr = (const float4*)(Wh + (size_t)p1_row*256);
    #pragma unroll
    for (int u = 0; u < 4; u++) whr[u] = wr[u*16 + part];
  }

  for (int t = 0; t < 64; t++){
    // ---------- P1 ----------
    if (t > 0){
      if (tid < 256){
        const float* sp = stats + ((size_t)p1_b*256 + tid)*16;
        float2 a0 = cld2(sp+0);  float2 b0 = cld2(sp+2);
        float2 a1 = cld2(sp+4);  float2 b1 = cld2(sp+6);
        float2 a2 = cld2(sp+8);  float2 b2 = cld2(sp+10);
        float2 a3 = cld2(sp+12); float2 b3 = cld2(sp+14);
        float m = fmaxf(fmaxf(a0.x, a1.x), fmaxf(a2.x, a3.x));
        float e0 = expf(a0.x - m), e1 = expf(a1.x - m), e2 = expf(a2.x - m), e3 = expf(a3.x - m);
        float den = a0.y*e0 + a1.y*e1 + a2.y*e2 + a3.y*e3;
        float num = b0.x*e0 + b1.x*e1 + b2.x*e2 + b3.x*e3;
        float hv = num/den + bao0;
        S[tid] = hv;
        if (p1_s == 0) cst(&hH[(size_t)t*2048 + p1_b*256 + tid], hv);
      }
    } else {
      if (tid < 256) S[tid] = 0.f;
    }
    __syncthreads();
    {
      const int j = tid >> 4, part = tid & 15;
      const float4* h4 = (const float4*)S;
      float a0 = 0.f;
      #pragma unroll
      for (int u = 0; u < 4; u++)
        a0 += dot4(whr[u], h4[u*16 + part]);
      a0 += __shfl_xor(a0, 1);
      a0 += __shfl_xor(a0, 2);
      a0 += __shfl_xor(a0, 4);
      a0 += __shfl_xor(a0, 8);
      if (part == 0) S[256 + j] = a0 + gx[(size_t)(t*8 + p1_b)*1024 + p1_row];
    }
    __syncthreads();
    if (tid < 8){
      const int o_ = p1_s*8 + tid, ci = p1_b*256 + o_;
      float ig = sigmf(S[256 + tid*4 + 0]);
      float fg = sigmf(S[256 + tid*4 + 1]);
      float gg = tanhf(S[256 + tid*4 + 2]);
      float ov = sigmf(S[256 + tid*4 + 3]);
      float cv = cld(&c[ci]);
      cst(&c[ci], fg*cv + ig*gg);
      cst(&og[ci], ov);
    }
    gbar(bar, ++ph);

    // ---------- P2: K[:, g=gid, :] = Wk16 . c ; vw[:, gid] ----------
    {
      int bb0 = tid >> 6, j40 = tid & 63;
      float* dst = &S[bb0*260 + j40*4];
      const float* src = &c[bb0*256 + j40*4];
      float2 v0 = cld2(src);
      float2 v1 = cld2(src+2);
      dst[0] = v0.x; dst[1] = v0.y; dst[2] = v1.x; dst[3] = v1.y;
    }
    __syncthreads();
    if (tid < 64){
      const int bb = tid >> 3, part = tid & 7;
      const float4* wv4 = (const float4*)(wve + gid*256);
      float sacc = 0.f;
      #pragma unroll
      for (int u = 0; u < 8; u++){
        float4 w = wv4[part*8 + u];
        const float* op = &og[bb*256 + (part*8 + u)*4];
        float2 o0 = cld2(op);
        float2 o1 = cld2(op+2);
        sacc += w.x*o0.x + w.y*o0.y + w.z*o1.x + w.w*o1.y;
      }
      sacc += __shfl_xor(sacc, 1);
      sacc += __shfl_xor(sacc, 2);
      sacc += __shfl_xor(sacc, 4);
      if (part == 0) cst(&vw[bb*256 + gid], sacc + bve[gid]);
    }
    {
      // 2-way k-split: d = tid>>1, kh = tid&1; coalesced Wk reads, broadcast c reads,
      // ONE shuffle per batch.
      const float4* cl4 = (const float4*)S;
      const int d = tid >> 1, kh = tid & 1;
      const __half* wr = wkh + ((size_t)gid*256 + d)*256 + kh*128;
      float acc[8];
      #pragma unroll
      for (int bb = 0; bb < 8; bb++) acc[bb] = 0.f;
      #pragma unroll 4
      for (int u = 0; u < 16; u++){
        uint4 wv = *(const uint4*)(wr + u*8);
        float4 w0, w1;
        h8_to_f8(wv, w0, w1);
        const int kk = kh*32 + u*2;
        #pragma unroll
        for (int bb = 0; bb < 8; bb++)
          acc[bb] += dot4(w0, cl4[bb*65 + kk]) + dot4(w1, cl4[bb*65 + kk + 1]);
      }
      const float bkv = bkb[gid*256 + d];
      #pragma unroll
      for (int bb = 0; bb < 8; bb++){
        acc[bb] += __shfl_xor(acc[bb], 1);
        if (kh == 0)
          cst(&Kt[(size_t)bb*65536 + gid*256 + d], acc[bb] + bkv);
      }
    }
    gbar(bar, ++ph);

    // ---------- P3: partial attention stats for (b, 32h, 64g) ----------
    {
      const __half* Qb = Qh + ((size_t)(t*8 + p3_b))*65536 + (size_t)p3_h0*256;
      #pragma unroll
      for (int i = 0; i < 2; i++){
        int f8 = i*512 + tid;
        int hh = f8 >> 5, j8 = f8 & 31;
        uint4 v = *(const uint4*)(Qb + hh*256 + j8*8);
        float4 a, b;
        h8_to_f8(v, a, b);
        float* dst = &S[hh*260 + j8*8];
        *(float4*)dst = a;
        *(float4*)(dst+4) = b;
      }
      const float* Kb = Kt + (size_t)p3_b*65536 + (size_t)p3_g0*256;
      float* Kl = S + 8320;
      #pragma unroll
      for (int i = 0; i < 8; i++){
        int f4 = i*512 + tid;
        int gg = f4 >> 6, j4 = (f4 & 63)*4;
        float* dst = &Kl[gg*260 + j4];
        const float* src = &Kb[gg*256 + j4];
        float2 v0 = cld2(src);
        float2 v1 = cld2(src+2);
        dst[0] = v0.x; dst[1] = v0.y; dst[2] = v1.x; dst[3] = v1.y;
      }
      if (tid < 64) S[24960 + tid] = cld(&vw[p3_b*256 + p3_g0 + tid]);
      __syncthreads();
      const int kh = tid >> 7, r = tid & 127, ty = r >> 4, txl = r & 15;
      float acc[4][4];
      #pragma unroll
      for (int a = 0; a < 4; a++)
        #pragma unroll
        for (int i = 0; i < 4; i++) acc[a][i] = 0.f;
      const float4* Ql4 = (const float4*)S;
      const float4* Kl4 = (const float4*)(S + 8320);
      for (int k4 = 0; k4 < 16; k4++){
        const int kk = kh*16 + k4;
        float4 qv[4], kv[4];
        #pragma unroll
        for (int a = 0; a < 4; a++) qv[a] = Ql4[(ty + 8*a)*65 + kk];
        #pragma unroll
        for (int i = 0; i < 4; i++) kv[i] = Kl4[(txl + 16*i)*65 + kk];
        #pragma unroll
        for (int a = 0; a < 4; a++)
          #pragma unroll
          for (int i = 0; i < 4; i++)
            acc[a][i] += dot4(qv[a], kv[i]);
      }
      __syncthreads();
      float* Pl = S;
      if (kh > 0){
        #pragma unroll
        for (int a = 0; a < 4; a++)
          #pragma unroll
          for (int i = 0; i < 4; i++)
            Pl[(kh-1)*2048 + r*16 + a*4 + i] = acc[a][i];
      }
      __syncthreads();
      if (kh == 0){
        #pragma unroll
        for (int p = 0; p < 3; p++)
          #pragma unroll
          for (int a = 0; a < 4; a++)
            #pragma unroll
            for (int i = 0; i < 4; i++)
              acc[a][i] += Pl[p*2048 + r*16 + a*4 + i];
        #pragma unroll
        for (int a = 0; a < 4; a++)
          #pragma unroll
          for (int i = 0; i < 4; i++)
            acc[a][i] *= 0.0625f;
        #pragma unroll
        for (int a = 0; a < 4; a++){
          float mx = fmaxf(fmaxf(acc[a][0], acc[a][1]), fmaxf(acc[a][2], acc[a][3]));
          mx = fmaxf(mx, __shfl_xor(mx, 1));
          mx = fmaxf(mx, __shfl_xor(mx, 2));
          mx = fmaxf(mx, __shfl_xor(mx, 4));
          mx = fmaxf(mx, __shfl_xor(mx, 8));
          float den = 0.f, num = 0.f;
          #pragma unroll
          for (int i = 0; i < 4; i++){
            float pv = expf(acc[a][i] - mx);
            den += pv;
            num += pv * S[24960 + txl + 16*i];
          }
          den += __shfl_xor(den, 1); num += __shfl_xor(num, 1);
          den += __shfl_xor(den, 2); num += __shfl_xor(num, 2);
          den += __shfl_xor(den, 4); num += __shfl_xor(num, 4);
          den += __shfl_xor(den, 8); num += __shfl_xor(num, 8);
          if (txl == 0){
            const int h = p3_h0 + ty + 8*a;
            float* sp = &stats[(((size_t)p3_b*256 + h)*4 + p3_gt)*4];
            cst2(sp, mx, den);
            cst(sp+2, num);
          }
        }
      }
    }
    bbar(bar, p3_b, ++phb);
  }

  // ---------- tail ----------
  if (p1_s == 0 && tid < 256){
    const float* sp = stats + ((size_t)p1_b*256 + tid)*16;
    float2 a0 = cld2(sp+0);  float2 b0 = cld2(sp+2);
    float2 a1 = cld2(sp+4);  float2 b1 = cld2(sp+6);
    float2 a2 = cld2(sp+8);  float2 b2 = cld2(sp+10);
    float2 a3 = cld2(sp+12); float2 b3 = cld2(sp+14);
    float m = fmaxf(fmaxf(a0.x, a1.x), fmaxf(a2.x, a3.x));
    float e0 = expf(a0.x - m), e1 = expf(a1.x - m), e2 = expf(a2.x - m), e3 = expf(a3.x - m);
    float den = a0.y*e0 + a1.y*e1 + a2.y*e2 + a3.y*e3;
    float num = b0.x*e0 + b1.x*e1 + b2.x*e2 + b3.x*e3;
    cst(&hH[(size_t)64*2048 + p1_b*256 + tid], num/den + bao0);
  }
  gbar(bar, ++ph);
  if (blk < 64 && tid < 80){
    const int t2 = blk;
    const int bb2 = tid/10, cc = tid - bb2*10;
    const float* hr = &hH[(size_t)(t2+1)*2048 + bb2*256];
    const float* wr2 = &Wout[cc*256];
    float acc = 0.f;
    for (int u = 0; u < 128; u++){
      float2 h2 = cld2(hr + u*2);
      acc += h2.x*wr2[u*2] + h2.y*wr2[u*2+1];
    }
    y[bb2*640 + cc*64 + t2] = acc + bout[cc];
  }
}

extern "C" void kernel_launch(void* const* d_in, const int* in_sizes, int n_in,
                              void* d_out, int out_size, void* d_ws, size_t ws_size,
                              hipStream_t stream){
  (void)in_sizes; (void)n_in; (void)out_size; (void)ws_size;
  const float* x      = (const float*)d_in[0];
  const float* w_init = (const float*)d_in[1];
  const float* b_init = (const float*)d_in[2];
  const float* c1w    = (const float*)d_in[3];
  const float* c1b    = (const float*)d_in[4];
  const float* c2w    = (const float*)d_in[5];
  const float* c2b    = (const float*)d_in[6];
  const float* c3w    = (const float*)d_in[7];
  const float* c3b    = (const float*)d_in[8];
  const float* Wx     = (const float*)d_in[9];
  const float* bx     = (const float*)d_in[10];
  const float* Wh     = (const float*)d_in[11];
  const float* bh     = (const float*)d_in[12];
  const float* Wxo    = (const float*)d_in[13];
  const float* bxo    = (const float*)d_in[14];
  const float* Wq     = (const float*)d_in[15];
  const float* bq     = (const float*)d_in[16];
  const float* Wk     = (const float*)d_in[17];
  const float* bk_    = (const float*)d_in[18];
  const float* Wv     = (const float*)d_in[19];
  const float* bv     = (const float*)d_in[20];
  const float* Wao    = (const float*)d_in[21];
  const float* bao    = (const float*)d_in[22];
  const float* Wout   = (const float*)d_in[23];
  const float* bout   = (const float*)d_in[24];
  float* y  = (float*)d_out;
  float* ws = (float*)d_ws;

  float* xin   = ws + WS_XIN;
  float* gf    = ws + WS_GF;
  float* stats = ws + WS_STATS;
  unsigned* bar = (unsigned*)(ws + WS_BARS);
  float* fs    = ws + WS_FS;
  float* xo    = ws + WS_XO;
  float* gxp   = ws + WS_GX;
  __half* Qh   = (__half*)(ws + WS_Q);
  __half* wkh  = (__half*)(ws + WS_WKH);
  __half* wqh  = (__half*)(ws + WS_WQH);
  float* wve   = ws + WS_WVE;
  float* bve   = ws + WS_BVE;
  float* Ktp   = ws + WS_KT;
  float* hH    = ws + WS_HH;
  float* cp    = ws + WS_C;
  float* ogp   = ws + WS_OG;
  float* vwp   = ws + WS_VW;

  k_init<<<256, 256, 0, stream>>>(x, ws);
  k_wk16<<<8192, 256, 0, stream>>>(Wk, wkh);
  k_wk16<<<8192, 256, 0, stream>>>(Wq, wqh);
  k_gemm_nt<<<dim3(8, 4), 256, 0, stream>>>(w_init, xin, b_init, nullptr, gf, 1024, 128, 1);
  k_feconv<<<512, 256, 0, stream>>>(gf, c1w, c1b, c2w, c2b, c3w, c3b, fs);
  k_gemm_nt<<<dim3(2, 4), 256, 0, stream>>>(Wxo, fs, bxo, nullptr, xo, 256, 256, 2);
  k_gemm_nt<<<dim3(8, 4), 256, 0, stream>>>(Wx, fs, bx, bh, gxp, 1024, 256, 0);
  k_wveff<<<256, 256, 0, stream>>>(Wv, bv, Wao, wve, bve, bar);
  k_gemmq<<<dim3(512, 4), 256, 0, stream>>>(wqh, xo, bq, Qh);
  k_loop<<<NBLK, 512, 0, stream>>>(gxp, Wh, wkh, bk_, wve, bve, Qh, bao, Wout, bout,
                                   cp, ogp, vwp, Ktp, stats, hH, y, bar);
}

// Round 18
// 2472.532 us; speedup vs baseline: 1.8146x; 1.0012x over previous
//
#include <hip/hip_runtime.h>
#include <hip/hip_fp16.h>
#include <math.h>

// Workspace layout (float offsets)
#define WS_XIN   0L
#define WS_GF    65536L
#define WS_STATS 65536L      // [8][256][4][4] softmax partials
#define WS_BARS  98304L      // barrier region: 8192 unsigned words
#define WS_FS    589824L
#define WS_XO    720896L
#define WS_GX    851968L
#define WS_Q     1376256L    // fp16 [512][65536]  -> ends 18153472
#define WS_WKH   18153472L   // fp16 [65536][256]  -> ends 26542080
#define WS_WQH   26542080L   // fp16 [65536][256]  -> ends 34930688
#define WS_WVE   34930688L
#define WS_BVE   34996224L
#define WS_KT    34996480L   // fp32 Kt[b][g][d]
#define WS_HH    35520768L   // [65][2048]
#define WS_C     35653888L
#define WS_OG    35655936L
#define WS_VW    35657984L

#define NBLK 256

typedef unsigned long long u64;
typedef _Float16 h2v __attribute__((ext_vector_type(2)));

__device__ __forceinline__ float sigmf(float x){ return 1.0f/(1.0f + expf(-x)); }
__device__ __forceinline__ float dot4(float4 a, float4 b){
  return a.x*b.x + a.y*b.y + a.z*b.z + a.w*b.w;
}
__device__ __forceinline__ void h8_to_f8(uint4 v, float4& a, float4& b){
  const __half2* hp = (const __half2*)&v;
  float2 f0 = __half22float2(hp[0]);
  float2 f1 = __half22float2(hp[1]);
  float2 f2 = __half22float2(hp[2]);
  float2 f3 = __half22float2(hp[3]);
  a = make_float4(f0.x, f0.y, f1.x, f1.y);
  b = make_float4(f2.x, f2.y, f3.x, f3.y);
}
__device__ __forceinline__ float4 h4_to_f4(uint2 v){
  const __half2* hp = (const __half2*)&v;
  float2 f0 = __half22float2(hp[0]);
  float2 f1 = __half22float2(hp[1]);
  return make_float4(f0.x, f0.y, f1.x, f1.y);
}
__device__ __forceinline__ float fdot2c(__half2 a, __half2 b, float c){
#if __has_builtin(__builtin_amdgcn_fdot2)
  h2v av = *(h2v*)&a;
  h2v bv = *(h2v*)&b;
  return __builtin_amdgcn_fdot2(av, bv, c, false);
#else
  float2 af = __half22float2(a);
  float2 bf = __half22float2(b);
  return fmaf(af.y, bf.y, fmaf(af.x, bf.x, c));
#endif
}

// coherent (device-point) accesses for cross-block mutable data — AGENT scope
__device__ __forceinline__ float cld(const float* p){
  return __hip_atomic_load((float*)p, __ATOMIC_RELAXED, __HIP_MEMORY_SCOPE_AGENT);
}
__device__ __forceinline__ void cst(float* p, float v){
  __hip_atomic_store(p, v, __ATOMIC_RELAXED, __HIP_MEMORY_SCOPE_AGENT);
}
__device__ __forceinline__ float2 cld2(const float* p){
  u64 v = __hip_atomic_load((const u64*)p, __ATOMIC_RELAXED, __HIP_MEMORY_SCOPE_AGENT);
  float2 r;
  r.x = __uint_as_float((unsigned)(v & 0xffffffffu));
  r.y = __uint_as_float((unsigned)(v >> 32));
  return r;
}
__device__ __forceinline__ void cst2(float* p, float a, float b){
  u64 v = ((u64)__float_as_uint(b) << 32) | (u64)__float_as_uint(a);
  __hip_atomic_store((u64*)p, v, __ATOMIC_RELAXED, __HIP_MEMORY_SCOPE_AGENT);
}
__device__ __forceinline__ unsigned cldu(const unsigned* p){
  return __hip_atomic_load((unsigned*)p, __ATOMIC_RELAXED, __HIP_MEMORY_SCOPE_AGENT);
}

// hierarchical full grid barrier: 32 groups x 8 blocks, monotonic phase counters.
__device__ __forceinline__ void gbar(unsigned* bar, unsigned ph){
  __syncthreads();
  if (threadIdx.x == 0){
    const unsigned g = blockIdx.x & 31u;
    asm volatile("s_waitcnt vmcnt(0)" ::: "memory");
    unsigned old = __hip_atomic_fetch_add(&bar[g*64], 1u, __ATOMIC_RELAXED, __HIP_MEMORY_SCOPE_AGENT);
    if (old == ph*8u - 1u){
      unsigned t = __hip_atomic_fetch_add(&bar[2048], 1u, __ATOMIC_RELAXED, __HIP_MEMORY_SCOPE_AGENT);
      if (t == ph*32u - 1u)
        __hip_atomic_store(&bar[2112], ph, __ATOMIC_RELAXED, __HIP_MEMORY_SCOPE_AGENT);
    }
    if (blockIdx.x < 32){
      while (cldu(&bar[2112]) < ph) __builtin_amdgcn_s_sleep(2);
      __hip_atomic_store(&bar[2176 + blockIdx.x*64], ph, __ATOMIC_RELAXED, __HIP_MEMORY_SCOPE_AGENT);
    } else {
      while (cldu(&bar[2176 + g*64]) < ph) __builtin_amdgcn_s_sleep(2);
    }
  }
  __syncthreads();
}

// per-batch barrier: 32 blocks (blk>>5 == b), counter at 6144 + b*64
__device__ __forceinline__ void bbar(unsigned* bar, int b, unsigned phb){
  __syncthreads();
  if (threadIdx.x == 0){
    unsigned* cnt = &bar[6144 + b*64];
    asm volatile("s_waitcnt vmcnt(0)" ::: "memory");
    __hip_atomic_fetch_add(cnt, 1u, __ATOMIC_RELAXED, __HIP_MEMORY_SCOPE_AGENT);
    while (cldu(cnt) < phb*32u) __builtin_amdgcn_s_sleep(2);
  }
  __syncthreads();
}

// ---------------- init
__launch_bounds__(256)
__global__ void k_init(const float* __restrict__ x, float* __restrict__ ws){
  int i = blockIdx.x*256 + threadIdx.x;
  int r = i >> 7, m = i & 127;
  int t = r >> 3, b = r & 7;
  ws[WS_XIN + i] = x[b*8192 + m*64 + t];
  if (i < 2048){ ws[WS_HH + i] = 0.f; ws[WS_C + i] = 0.f; }
}

// ---------------- fp32 -> fp16 bulk convert
__launch_bounds__(256)
__global__ void k_wk16(const float* __restrict__ in, __half* __restrict__ out){
  size_t i = ((size_t)blockIdx.x*256 + threadIdx.x)*8;
  float4 a = *(const float4*)(in + i);
  float4 b = *(const float4*)(in + i + 4);
  uint4 v;
  __half2* vp = (__half2*)&v;
  vp[0] = __floats2half2_rn(a.x, a.y);
  vp[1] = __floats2half2_rn(a.z, a.w);
  vp[2] = __floats2half2_rn(b.x, b.y);
  vp[3] = __floats2half2_rn(b.z, b.w);
  *(uint4*)(out + i) = v;
}

// ---------------- generic fp32 GEMM (act: 0 none, 1 relu, 2 sigmoid)
__launch_bounds__(256)
__global__ void k_gemm_nt(const float* __restrict__ W, const float* __restrict__ X,
                          const float* __restrict__ b1, const float* __restrict__ b2,
                          float* __restrict__ out, int M, int K, int act){
  __shared__ float Wt[32*132];
  __shared__ float Xt[32*132];
  const int tid = threadIdx.x;
  const int tx = tid & 15, ty = tid >> 4;
  const int m0 = blockIdx.x * 128, n0 = blockIdx.y * 128;
  float acc[8][8];
  #pragma unroll
  for (int i = 0; i < 8; i++)
    #pragma unroll
    for (int j = 0; j < 8; j++) acc[i][j] = 0.f;

  for (int k0 = 0; k0 < K; k0 += 32){
    #pragma unroll
    for (int i = 0; i < 4; i++){
      int f4 = i*256 + tid;
      int row = f4 >> 3;
      int j4 = (f4 & 7) * 4;
      float4 w = *(const float4*)&W[(size_t)(m0+row)*K + k0 + j4];
      Wt[(j4+0)*132 + row] = w.x;
      Wt[(j4+1)*132 + row] = w.y;
      Wt[(j4+2)*132 + row] = w.z;
      Wt[(j4+3)*132 + row] = w.w;
      float4 xv = *(const float4*)&X[(size_t)(n0+row)*K + k0 + j4];
      Xt[(j4+0)*132 + row] = xv.x;
      Xt[(j4+1)*132 + row] = xv.y;
      Xt[(j4+2)*132 + row] = xv.z;
      Xt[(j4+3)*132 + row] = xv.w;
    }
    __syncthreads();
    for (int k = 0; k < 32; k++){
      float4 a0 = *(const float4*)&Wt[k*132 + 4*tx];
      float4 a1 = *(const float4*)&Wt[k*132 + 64 + 4*tx];
      float4 x0 = *(const float4*)&Xt[k*132 + 4*ty];
      float4 x1 = *(const float4*)&Xt[k*132 + 64 + 4*ty];
      float am[8] = {a0.x,a0.y,a0.z,a0.w,a1.x,a1.y,a1.z,a1.w};
      float xn[8] = {x0.x,x0.y,x0.z,x0.w,x1.x,x1.y,x1.z,x1.w};
      #pragma unroll
      for (int mi = 0; mi < 8; mi++)
        #pragma unroll
        for (int ni = 0; ni < 8; ni++)
          acc[mi][ni] += am[mi]*xn[ni];
    }
    __syncthreads();
  }

  float bvv[8];
  #pragma unroll
  for (int mi = 0; mi < 8; mi++){
    int m = m0 + ((mi < 4) ? (4*tx + mi) : (64 + 4*tx + mi - 4));
    float bb = b1[m];
    if (b2) bb += b2[m];
    bvv[mi] = bb;
  }
  #pragma unroll
  for (int ni = 0; ni < 8; ni++){
    int n = n0 + ((ni < 4) ? (4*ty + ni) : (64 + 4*ty + ni - 4));
    float v[8];
    #pragma unroll
    for (int mi = 0; mi < 8; mi++){
      float q = acc[mi][ni] + bvv[mi];
      if (act == 1) q = fmaxf(q, 0.f);
      else if (act == 2) q = 1.0f/(1.0f + expf(-q));
      v[mi] = q;
    }
    *(float4*)&out[(size_t)n*M + m0 + 4*tx]      = make_float4(v[0],v[1],v[2],v[3]);
    *(float4*)&out[(size_t)n*M + m0 + 64 + 4*tx] = make_float4(v[4],v[5],v[6],v[7]);
  }
}

// ---------------- Q GEMM (fp16 operands, fdot2)
__launch_bounds__(256)
__global__ void k_gemmq(const __half* __restrict__ Wh, const float* __restrict__ X,
                        const float* __restrict__ b1, __half* __restrict__ out){
  __shared__ __half2 Wt[16*132];
  __shared__ __half2 Xt[16*132];
  const int tid = threadIdx.x;
  const int tx = tid & 15, ty = tid >> 4;
  const int m0 = blockIdx.x * 128, n0 = blockIdx.y * 128;
  float acc[8][8];
  #pragma unroll
  for (int i = 0; i < 8; i++)
    #pragma unroll
    for (int j = 0; j < 8; j++) acc[i][j] = 0.f;

  for (int k0 = 0; k0 < 256; k0 += 32){
    #pragma unroll
    for (int i = 0; i < 2; i++){
      int f = i*256 + tid;
      int row = f >> 2, q = f & 3;
      uint4 wv = *(const uint4*)(Wh + (size_t)(m0+row)*256 + k0 + q*8);
      const __half2* wp = (const __half2*)&wv;
      #pragma unroll
      for (int j = 0; j < 4; j++)
        Wt[(q*4 + j)*132 + row] = wp[j];
    }
    #pragma unroll
    for (int i = 0; i < 4; i++){
      int f = i*256 + tid;
      int row = f >> 3, q = f & 7;
      float4 xv = *(const float4*)&X[(size_t)(n0+row)*256 + k0 + q*4];
      Xt[(q*2    )*132 + row] = __floats2half2_rn(xv.x, xv.y);
      Xt[(q*2 + 1)*132 + row] = __floats2half2_rn(xv.z, xv.w);
    }
    __syncthreads();
    for (int k2 = 0; k2 < 16; k2++){
      __half2 am[8], xn[8];
      #pragma unroll
      for (int s = 0; s < 4; s++){
        am[s]   = Wt[k2*132 + 4*tx + s];
        am[4+s] = Wt[k2*132 + 64 + 4*tx + s];
        xn[s]   = Xt[k2*132 + 4*ty + s];
        xn[4+s] = Xt[k2*132 + 64 + 4*ty + s];
      }
      #pragma unroll
      for (int mi = 0; mi < 8; mi++)
        #pragma unroll
        for (int ni = 0; ni < 8; ni++)
          acc[mi][ni] = fdot2c(am[mi], xn[ni], acc[mi][ni]);
    }
    __syncthreads();
  }

  float bvv[8];
  #pragma unroll
  for (int mi = 0; mi < 8; mi++){
    int m = m0 + ((mi < 4) ? (4*tx + mi) : (64 + 4*tx + mi - 4));
    bvv[mi] = b1[m];
  }
  #pragma unroll
  for (int ni = 0; ni < 8; ni++){
    int n = n0 + ((ni < 4) ? (4*ty + ni) : (64 + 4*ty + ni - 4));
    float v[8];
    #pragma unroll
    for (int mi = 0; mi < 8; mi++) v[mi] = acc[mi][ni] + bvv[mi];
    uint2 u0, u1;
    __half2* up0 = (__half2*)&u0;
    __half2* up1 = (__half2*)&u1;
    up0[0] = __floats2half2_rn(v[0], v[1]);
    up0[1] = __floats2half2_rn(v[2], v[3]);
    up1[0] = __floats2half2_rn(v[4], v[5]);
    up1[1] = __floats2half2_rn(v[6], v[7]);
    *(uint2*)&out[(size_t)n*65536 + m0 + 4*tx]      = u0;
    *(uint2*)&out[(size_t)n*65536 + m0 + 64 + 4*tx] = u1;
  }
}

// ---------------- feature extractor conv chain
__launch_bounds__(256)
__global__ void k_feconv(const float* __restrict__ gf, const float* __restrict__ c1w,
                         const float* __restrict__ c1b, const float* __restrict__ c2w,
                         const float* __restrict__ c2b, const float* __restrict__ c3w,
                         const float* __restrict__ c3b, float* __restrict__ fs){
  __shared__ float fc[1024];
  __shared__ float p1[16*512];
  __shared__ float p2[32*256];
  __shared__ float w1[48], w2[1536], w3[96], bb1[16], bb2[32];
  const int r = blockIdx.x, tid = threadIdx.x;
  #pragma unroll
  for (int i = 0; i < 4; i++) fc[i*256 + tid] = gf[(size_t)r*1024 + i*256 + tid];
  if (tid < 48) w1[tid] = c1w[tid];
  if (tid < 16) bb1[tid] = c1b[tid];
  for (int i = tid; i < 1536; i += 256) w2[i] = c2w[i];
  if (tid < 32) bb2[tid] = c2b[tid];
  if (tid < 96) w3[tid] = c3w[tid];
  __syncthreads();
  for (int i = 0; i < 32; i++){
    int idx = i*256 + tid;
    int ch = idx >> 9, p = idx & 511;
    float k0 = w1[ch*3], k1 = w1[ch*3+1], k2 = w1[ch*3+2], bias = bb1[ch];
    int q = 2*p;
    float xm1 = (q >= 1) ? fc[q-1] : 0.f;
    float x0 = fc[q];
    float x1 = fc[q+1];
    float x2 = (q+2 < 1024) ? fc[q+2] : 0.f;
    float a0 = bias + k0*xm1 + k1*x0 + k2*x1;
    float a1 = bias + k0*x0 + k1*x1 + k2*x2;
    p1[ch*512 + p] = fmaxf(fmaxf(a0, 0.f), fmaxf(a1, 0.f));
  }
  __syncthreads();
  for (int i = 0; i < 32; i++){
    int idx = i*256 + tid;
    int ch = idx >> 8, p = idx & 255;
    float a0 = bb2[ch], a1 = bb2[ch];
    int q = 2*p;
    #pragma unroll
    for (int ci = 0; ci < 16; ci++){
      const float* wp = &w2[(ch*16+ci)*3];
      const float* ip = &p1[ci*512];
      float xm1 = (q >= 1) ? ip[q-1] : 0.f;
      float x0 = ip[q];
      float x1 = ip[q+1];
      float x2 = (q+2 < 512) ? ip[q+2] : 0.f;
      a0 += wp[0]*xm1 + wp[1]*x0 + wp[2]*x1;
      a1 += wp[0]*x0  + wp[1]*x1 + wp[2]*x2;
    }
    p2[ch*256 + p] = fmaxf(fmaxf(a0, 0.f), fmaxf(a1, 0.f));
  }
  __syncthreads();
  if (tid < 256){
    float a = c3b[0];
    const int l = tid;
    #pragma unroll
    for (int ci = 0; ci < 32; ci++){
      const float* wp = &w3[ci*3];
      const float* ip = &p2[ci*256];
      float xm1 = (l >= 1) ? ip[l-1] : 0.f;
      float x0 = ip[l];
      float x2 = (l+1 < 256) ? ip[l+1] : 0.f;
      a += wp[0]*xm1 + wp[1]*x0 + wp[2]*x2;
    }
    fs[(size_t)r*256 + l] = a;
  }
}

// ---------------- Wv_eff + barrier region init
__launch_bounds__(256)
__global__ void k_wveff(const float* __restrict__ Wv, const float* __restrict__ bvq,
                        const float* __restrict__ Wao, float* __restrict__ wve,
                        float* __restrict__ bve, unsigned* __restrict__ bar){
  __shared__ float wa[256];
  const int g = blockIdx.x, tid = threadIdx.x;
  if (g == 0){
    for (int i = tid; i < 8192; i += 256) bar[i] = 0u;
  }
  wa[tid] = Wao[tid];
  __syncthreads();
  float acc = 0.f;
  for (int d = 0; d < 256; d++)
    acc += Wv[((size_t)(g*256 + d))*256 + tid] * wa[d];
  wve[g*256 + tid] = acc;
  if (tid == 0){
    float s = 0.f;
    for (int d = 0; d < 256; d++) s += bvq[g*256 + d]*wa[d];
    bve[g] = s;
  }
}

// ---------------- persistent recurrent loop (best-known-good: R15 configuration)
__global__ __launch_bounds__(512, 2)
void k_loop(const float* __restrict__ gx, const float* __restrict__ Wh,
            const __half* __restrict__ wkh, const float* __restrict__ bkb,
            const float* __restrict__ wve, const float* __restrict__ bve,
            const __half* __restrict__ Qh, const float* __restrict__ bao,
            const float* __restrict__ Wout, const float* __restrict__ bout,
            float* __restrict__ c, float* __restrict__ og, float* __restrict__ vw,
            float* __restrict__ Kt, float* __restrict__ stats, float* __restrict__ hH,
            float* __restrict__ y, unsigned* __restrict__ bar){
  __shared__ float S[25088];
  const int blk = blockIdx.x, tid = threadIdx.x;
  unsigned ph = 0, phb = 0;
  const float bao0 = bao[0];

  const int p1_b = blk >> 5, p1_s = blk & 31;
  const int gid  = blk;
  const int p3_b = blk >> 5, p3_ht = (blk >> 2) & 7, p3_gt = blk & 3;
  const int p3_h0 = p3_ht*32, p3_g0 = p3_gt*64;

  // hoist Wh fragment for P1
  float4 whr[4];
  int p1_row;
  {
    const int j = tid >> 4, part = tid & 15;
    const int rr = p1_s*32 + j, o = rr >> 2, gate = rr & 3;
    p1_row = gate*256 + o;
    const float4* wr = (const float4*)(Wh + (size_t)p1_row*256);
    #pragma unroll
    for (int u = 0; u < 4; u++) whr[u] = wr[u*16 + part];
  }

  for (int t = 0; t < 64; t++){
    // ---------- P1 ----------
    if (t > 0){
      if (tid < 256){
        const float* sp = stats + ((size_t)p1_b*256 + tid)*16;
        float2 a0 = cld2(sp+0);  float2 b0 = cld2(sp+2);
        float2 a1 = cld2(sp+4);  float2 b1 = cld2(sp+6);
        float2 a2 = cld2(sp+8);  float2 b2 = cld2(sp+10);
        float2 a3 = cld2(sp+12); float2 b3 = cld2(sp+14);
        float m = fmaxf(fmaxf(a0.x, a1.x), fmaxf(a2.x, a3.x));
        float e0 = expf(a0.x - m), e1 = expf(a1.x - m), e2 = expf(a2.x - m), e3 = expf(a3.x - m);
        float den = a0.y*e0 + a1.y*e1 + a2.y*e2 + a3.y*e3;
        float num = b0.x*e0 + b1.x*e1 + b2.x*e2 + b3.x*e3;
        float hv = num/den + bao0;
        S[tid] = hv;
        if (p1_s == 0) cst(&hH[(size_t)t*2048 + p1_b*256 + tid], hv);
      }
    } else {
      if (tid < 256) S[tid] = 0.f;
    }
    __syncthreads();
    {
      const int j = tid >> 4, part = tid & 15;
      const float4* h4 = (const float4*)S;
      float a0 = 0.f;
      #pragma unroll
      for (int u = 0; u < 4; u++)
        a0 += dot4(whr[u], h4[u*16 + part]);
      a0 += __shfl_xor(a0, 1);
      a0 += __shfl_xor(a0, 2);
      a0 += __shfl_xor(a0, 4);
      a0 += __shfl_xor(a0, 8);
      if (part == 0) S[256 + j] = a0 + gx[(size_t)(t*8 + p1_b)*1024 + p1_row];
    }
    __syncthreads();
    if (tid < 8){
      const int o_ = p1_s*8 + tid, ci = p1_b*256 + o_;
      float ig = sigmf(S[256 + tid*4 + 0]);
      float fg = sigmf(S[256 + tid*4 + 1]);
      float gg = tanhf(S[256 + tid*4 + 2]);
      float ov = sigmf(S[256 + tid*4 + 3]);
      float cv = cld(&c[ci]);
      cst(&c[ci], fg*cv + ig*gg);
      cst(&og[ci], ov);
    }
    gbar(bar, ++ph);

    // ---------- P2: K[:, g=gid, :] = Wk16 . c ; vw[:, gid] ----------
    {
      int bb0 = tid >> 6, j40 = tid & 63;
      float* dst = &S[bb0*260 + j40*4];
      const float* src = &c[bb0*256 + j40*4];
      float2 v0 = cld2(src);
      float2 v1 = cld2(src+2);
      dst[0] = v0.x; dst[1] = v0.y; dst[2] = v1.x; dst[3] = v1.y;
    }
    __syncthreads();
    if (tid < 64){
      const int bb = tid >> 3, part = tid & 7;
      const float4* wv4 = (const float4*)(wve + gid*256);
      float sacc = 0.f;
      #pragma unroll
      for (int u = 0; u < 8; u++){
        float4 w = wv4[part*8 + u];
        const float* op = &og[bb*256 + (part*8 + u)*4];
        float2 o0 = cld2(op);
        float2 o1 = cld2(op+2);
        sacc += w.x*o0.x + w.y*o0.y + w.z*o1.x + w.w*o1.y;
      }
      sacc += __shfl_xor(sacc, 1);
      sacc += __shfl_xor(sacc, 2);
      sacc += __shfl_xor(sacc, 4);
      if (part == 0) cst(&vw[bb*256 + gid], sacc + bve[gid]);
    }
    {
      const float4* cl4 = (const float4*)S;
      const int d = tid >> 1, kh = tid & 1;
      const __half* wr = wkh + ((size_t)gid*256 + d)*256 + kh*128;
      float acc[8];
      #pragma unroll
      for (int bb = 0; bb < 8; bb++) acc[bb] = 0.f;
      #pragma unroll 4
      for (int u = 0; u < 16; u++){
        uint4 wv = *(const uint4*)(wr + u*8);
        float4 w0, w1;
        h8_to_f8(wv, w0, w1);
        const int kk = kh*32 + u*2;
        #pragma unroll
        for (int bb = 0; bb < 8; bb++)
          acc[bb] += dot4(w0, cl4[bb*65 + kk]) + dot4(w1, cl4[bb*65 + kk + 1]);
      }
      const float bkv = bkb[gid*256 + d];
      #pragma unroll
      for (int bb = 0; bb < 8; bb++){
        acc[bb] += __shfl_xor(acc[bb], 1);
        if (kh == 0)
          cst(&Kt[(size_t)bb*65536 + gid*256 + d], acc[bb] + bkv);
      }
    }
    gbar(bar, ++ph);

    // ---------- P3: partial attention stats for (b, 32h, 64g) ----------
    {
      const __half* Qb = Qh + ((size_t)(t*8 + p3_b))*65536 + (size_t)p3_h0*256;
      #pragma unroll
      for (int i = 0; i < 2; i++){
        int f8 = i*512 + tid;
        int hh = f8 >> 5, j8 = f8 & 31;
        uint4 v = *(const uint4*)(Qb + hh*256 + j8*8);
        float4 a, b;
        h8_to_f8(v, a, b);
        float* dst = &S[hh*260 + j8*8];
        *(float4*)dst = a;
        *(float4*)(dst+4) = b;
      }
      const float* Kb = Kt + (size_t)p3_b*65536 + (size_t)p3_g0*256;
      float* Kl = S + 8320;
      #pragma unroll
      for (int i = 0; i < 8; i++){
        int f4 = i*512 + tid;
        int gg = f4 >> 6, j4 = (f4 & 63)*4;
        float* dst = &Kl[gg*260 + j4];
        const float* src = &Kb[gg*256 + j4];
        float2 v0 = cld2(src);
        float2 v1 = cld2(src+2);
        dst[0] = v0.x; dst[1] = v0.y; dst[2] = v1.x; dst[3] = v1.y;
      }
      if (tid < 64) S[24960 + tid] = cld(&vw[p3_b*256 + p3_g0 + tid]);
      __syncthreads();
      const int kh = tid >> 7, r = tid & 127, ty = r >> 4, txl = r & 15;
      float acc[4][4];
      #pragma unroll
      for (int a = 0; a < 4; a++)
        #pragma unroll
        for (int i = 0; i < 4; i++) acc[a][i] = 0.f;
      const float4* Ql4 = (const float4*)S;
      const float4* Kl4 = (const float4*)(S + 8320);
      for (int k4 = 0; k4 < 16; k4++){
        const int kk = kh*16 + k4;
        float4 qv[4], kv[4];
        #pragma unroll
        for (int a = 0; a < 4; a++) qv[a] = Ql4[(ty + 8*a)*65 + kk];
        #pragma unroll
        for (int i = 0; i < 4; i++) kv[i] = Kl4[(txl + 16*i)*65 + kk];
        #pragma unroll
        for (int a = 0; a < 4; a++)
          #pragma unroll
          for (int i = 0; i < 4; i++)
            acc[a][i] += dot4(qv[a], kv[i]);
      }
      __syncthreads();
      float* Pl = S;
      if (kh > 0){
        #pragma unroll
        for (int a = 0; a < 4; a++)
          #pragma unroll
          for (int i = 0; i < 4; i++)
            Pl[(kh-1)*2048 + r*16 + a*4 + i] = acc[a][i];
      }
      __syncthreads();
      if (kh == 0){
        #pragma unroll
        for (int p = 0; p < 3; p++)
          #pragma unroll
          for (int a = 0; a < 4; a++)
            #pragma unroll
            for (int i = 0; i < 4; i++)
              acc[a][i] += Pl[p*2048 + r*16 + a*4 + i];
        #pragma unroll
        for (int a = 0; a < 4; a++)
          #pragma unroll
          for (int i = 0; i < 4; i++)
            acc[a][i] *= 0.0625f;
        #pragma unroll
        for (int a = 0; a < 4; a++){
          float mx = fmaxf(fmaxf(acc[a][0], acc[a][1]), fmaxf(acc[a][2], acc[a][3]));
          mx = fmaxf(mx, __shfl_xor(mx, 1));
          mx = fmaxf(mx, __shfl_xor(mx, 2));
          mx = fmaxf(mx, __shfl_xor(mx, 4));
          mx = fmaxf(mx, __shfl_xor(mx, 8));
          float den = 0.f, num = 0.f;
          #pragma unroll
          for (int i = 0; i < 4; i++){
            float pv = expf(acc[a][i] - mx);
            den += pv;
            num += pv * S[24960 + txl + 16*i];
          }
          den += __shfl_xor(den, 1); num += __shfl_xor(num, 1);
          den += __shfl_xor(den, 2); num += __shfl_xor(num, 2);
          den += __shfl_xor(den, 4); num += __shfl_xor(num, 4);
          den += __shfl_xor(den, 8); num += __shfl_xor(num, 8);
          if (txl == 0){
            const int h = p3_h0 + ty + 8*a;
            float* sp = &stats[(((size_t)p3_b*256 + h)*4 + p3_gt)*4];
            cst2(sp, mx, den);
            cst(sp+2, num);
          }
        }
      }
    }
    bbar(bar, p3_b, ++phb);
  }

  // ---------- tail ----------
  if (p1_s == 0 && tid < 256){
    const float* sp = stats + ((size_t)p1_b*256 + tid)*16;
    float2 a0 = cld2(sp+0);  float2 b0 = cld2(sp+2);
    float2 a1 = cld2(sp+4);  float2 b1 = cld2(sp+6);
    float2 a2 = cld2(sp+8);  float2 b2 = cld2(sp+10);
    float2 a3 = cld2(sp+12); float2 b3 = cld2(sp+14);
    float m = fmaxf(fmaxf(a0.x, a1.x), fmaxf(a2.x, a3.x));
    float e0 = expf(a0.x - m), e1 = expf(a1.x - m), e2 = expf(a2.x - m), e3 = expf(a3.x - m);
    float den = a0.y*e0 + a1.y*e1 + a2.y*e2 + a3.y*e3;
    float num = b0.x*e0 + b1.x*e1 + b2.x*e2 + b3.x*e3;
    cst(&hH[(size_t)64*2048 + p1_b*256 + tid], num/den + bao0);
  }
  gbar(bar, ++ph);
  if (blk < 64 && tid < 80){
    const int t2 = blk;
    const int bb2 = tid/10, cc = tid - bb2*10;
    const float* hr = &hH[(size_t)(t2+1)*2048 + bb2*256];
    const float* wr2 = &Wout[cc*256];
    float acc = 0.f;
    for (int u = 0; u < 128; u++){
      float2 h2 = cld2(hr + u*2);
      acc += h2.x*wr2[u*2] + h2.y*wr2[u*2+1];
    }
    y[bb2*640 + cc*64 + t2] = acc + bout[cc];
  }
}

extern "C" void kernel_launch(void* const* d_in, const int* in_sizes, int n_in,
                              void* d_out, int out_size, void* d_ws, size_t ws_size,
                              hipStream_t stream){
  (void)in_sizes; (void)n_in; (void)out_size; (void)ws_size;
  const float* x      = (const float*)d_in[0];
  const float* w_init = (const float*)d_in[1];
  const float* b_init = (const float*)d_in[2];
  const float* c1w    = (const float*)d_in[3];
  const float* c1b    = (const float*)d_in[4];
  const float* c2w    = (const float*)d_in[5];
  const float* c2b    = (const float*)d_in[6];
  const float* c3w    = (const float*)d_in[7];
  const float* c3b    = (const float*)d_in[8];
  const float* Wx     = (const float*)d_in[9];
  const float* bx     = (const float*)d_in[10];
  const float* Wh     = (const float*)d_in[11];
  const float* bh     = (const float*)d_in[12];
  const float* Wxo    = (const float*)d_in[13];
  const float* bxo    = (const float*)d_in[14];
  const float* Wq     = (const float*)d_in[15];
  const float* bq     = (const float*)d_in[16];
  const float* Wk     = (const float*)d_in[17];
  const float* bk_    = (const float*)d_in[18];
  const float* Wv     = (const float*)d_in[19];
  const float* bv     = (const float*)d_in[20];
  const float* Wao    = (const float*)d_in[21];
  const float* bao    = (const float*)d_in[22];
  const float* Wout   = (const float*)d_in[23];
  const float* bout   = (const float*)d_in[24];
  float* y  = (float*)d_out;
  float* ws = (float*)d_ws;

  float* xin   = ws + WS_XIN;
  float* gf    = ws + WS_GF;
  float* stats = ws + WS_STATS;
  unsigned* bar = (unsigned*)(ws + WS_BARS);
  float* fs    = ws + WS_FS;
  float* xo    = ws + WS_XO;
  float* gxp   = ws + WS_GX;
  __half* Qh   = (__half*)(ws + WS_Q);
  __half* wkh  = (__half*)(ws + WS_WKH);
  __half* wqh  = (__half*)(ws + WS_WQH);
  float* wve   = ws + WS_WVE;
  float* bve   = ws + WS_BVE;
  float* Ktp   = ws + WS_KT;
  float* hH    = ws + WS_HH;
  float* cp    = ws + WS_C;
  float* ogp   = ws + WS_OG;
  float* vwp   = ws + WS_VW;

  k_init<<<256, 256, 0, stream>>>(x, ws);
  k_wk16<<<8192, 256, 0, stream>>>(Wk, wkh);
  k_wk16<<<8192, 256, 0, stream>>>(Wq, wqh);
  k_gemm_nt<<<dim3(8, 4), 256, 0, stream>>>(w_init, xin, b_init, nullptr, gf, 1024, 128, 1);
  k_feconv<<<512, 256, 0, stream>>>(gf, c1w, c1b, c2w, c2b, c3w, c3b, fs);
  k_gemm_nt<<<dim3(2, 4), 256, 0, stream>>>(Wxo, fs, bxo, nullptr, xo, 256, 256, 2);
  k_gemm_nt<<<dim3(8, 4), 256, 0, stream>>>(Wx, fs, bx, bh, gxp, 1024, 256, 0);
  k_wveff<<<256, 256, 0, stream>>>(Wv, bv, Wao, wve, bve, bar);
  k_gemmq<<<dim3(512, 4), 256, 0, stream>>>(wqh, xo, bq, Qh);
  k_loop<<<NBLK, 512, 0, stream>>>(gxp, Wh, wkh, bk_, wve, bve, Qh, bao, Wout, bout,
                                   cp, ogp, vwp, Ktp, stats, hH, y, bar);
}